// Round 5
// baseline (1441.035 us; speedup 1.0000x reference)
//
#include <hip/hip_runtime.h>

#define D 128
#define BM 64

typedef short short8 __attribute__((ext_vector_type(8)));
typedef unsigned short ushort8_t __attribute__((ext_vector_type(8)));
typedef float f32x4 __attribute__((ext_vector_type(4)));

__device__ __forceinline__ unsigned short f2bf(float x) {
    unsigned u = __float_as_uint(x);
    unsigned r = (u + 0x7fffu + ((u >> 16) & 1u)) >> 16;   // RNE
    return (unsigned short)r;
}
__device__ __forceinline__ float bf2f(unsigned short u) {
    return __uint_as_float(((unsigned)u) << 16);
}

// ===========================================================================
// features fp32 -> bf16 (linear layout)
// ===========================================================================
__global__ __launch_bounds__(256) void fconv_kernel(
    const float4* __restrict__ feat4, ushort4* __restrict__ fbf4, int total)
{
    int i = blockIdx.x * 256 + threadIdx.x;
    if (i < total) {
        float4 v = feat4[i];
        fbf4[i] = make_ushort4(f2bf(v.x), f2bf(v.y), f2bf(v.z), f2bf(v.w));
    }
}

// ===========================================================================
// W -> WT bf16: WT[c][k] = (k<128 ? W1[k][c] : W2[k-128][c]), [128][256]
// ===========================================================================
__global__ __launch_bounds__(256) void wconv_kernel(
    const float* __restrict__ W1, const float* __restrict__ W2,
    unsigned short* __restrict__ WT)
{
    int idx = blockIdx.x * 256 + threadIdx.x;   // 32768
    int c = idx & 127;
    int k = idx >> 7;
    float w = (k < 128) ? W1[k * 128 + c] : W2[(k - 128) * 128 + c];
    WT[c * 256 + k] = f2bf(w);
}

// ===========================================================================
// Bucket path (tier-1): 128-row buckets; no global sort, no N-sized scan.
// ===========================================================================

// Per-block LDS histogram -> one global atomicAdd per (block,bucket).
__global__ __launch_bounds__(256) void bucket_hist_kernel(
    const int* __restrict__ rows, int* __restrict__ bcnt, int E, int nb, int epb)
{
    __shared__ int cnt[1024];
    int t = threadIdx.x;
    for (int i = t; i < nb; i += 256) cnt[i] = 0;
    __syncthreads();
    int e0 = blockIdx.x * epb;
    int e1 = e0 + epb; if (e1 > E) e1 = E;
    for (int e = e0 + t; e < e1; e += 256) atomicAdd(&cnt[rows[e] >> 7], 1);
    __syncthreads();
    for (int i = t; i < nb; i += 256)
        if (cnt[i]) atomicAdd(&bcnt[i], cnt[i]);
}

// Exclusive scan of nb (<=1024) bucket counts -> bstart, bcur; bstart[nb]=E.
__global__ __launch_bounds__(1024) void bucket_scan_kernel(
    const int* __restrict__ bcnt, int* __restrict__ bstart,
    int* __restrict__ bcur, int nb, int E)
{
    __shared__ int wsum[16];
    int tid = threadIdx.x, lane = tid & 63, wid = tid >> 6;
    int x = (tid < nb) ? bcnt[tid] : 0;
    int v = x;
    #pragma unroll
    for (int off = 1; off < 64; off <<= 1) {
        int y = __shfl_up(v, off, 64);
        if (lane >= off) v += y;
    }
    if (lane == 63) wsum[wid] = v;
    __syncthreads();
    if (wid == 0 && lane < 16) {
        int s = wsum[lane];
        #pragma unroll
        for (int off = 1; off < 16; off <<= 1) {
            int y = __shfl_up(s, off, 64);
            if (lane >= off) s += y;
        }
        wsum[lane] = s;
    }
    __syncthreads();
    int wexcl = wid ? wsum[wid - 1] : 0;
    int excl = wexcl + v - x;
    if (tid < nb) { bstart[tid] = excl; bcur[tid] = excl; }
    if (tid == 0) bstart[nb] = E;
}

// 4096 edges/block: LDS hist -> reserve run per bucket -> write runs.
// Edge packed: key = (r&127)<<17 | col  (needs N <= 2^17), val fp32 bits.
__global__ __launch_bounds__(256) void bucket_scatter_kernel(
    const int* __restrict__ rows, const int* __restrict__ cols,
    const float* __restrict__ vals, int* __restrict__ bcur,
    uint2* __restrict__ bsedge, int E, int nb)
{
    __shared__ int cnt[1024];
    __shared__ int base[1024];
    int t = threadIdx.x;
    int e0 = blockIdx.x * 4096;
    for (int i = t; i < nb; i += 256) cnt[i] = 0;
    __syncthreads();
    #pragma unroll
    for (int q = 0; q < 16; ++q) {
        int e = e0 + t + q * 256;
        if (e < E) atomicAdd(&cnt[rows[e] >> 7], 1);
    }
    __syncthreads();
    for (int i = t; i < nb; i += 256) {
        int c = cnt[i];
        if (c) { base[i] = atomicAdd(&bcur[i], c); cnt[i] = 0; }
    }
    __syncthreads();
    #pragma unroll
    for (int q = 0; q < 16; ++q) {
        int e = e0 + t + q * 256;
        if (e < E) {
            int r = rows[e];
            int b = r >> 7;
            int pos = base[b] + atomicAdd(&cnt[b], 1);
            bsedge[pos] = make_uint2(((unsigned)(r & 127) << 17) | (unsigned)cols[e],
                                     __float_as_uint(vals[e]));
        }
    }
}

// One block per 128-row bucket; 64KB LDS fp32 accumulator; LDS float atomics.
// Wave handles 4 consecutive edges per iteration (independent gathers).
// Emits a=(f+h), m=(f*h) bf16 into ambf[row][512B], pre-swizzled for the GEMM.
__global__ __launch_bounds__(512) void spmm_bucket_kernel(
    const float4* __restrict__ feat4,
    const unsigned* __restrict__ fbfu,
    const int* __restrict__ bstart,
    const uint2* __restrict__ bsedge,
    unsigned char* __restrict__ ambf, int N)
{
    __shared__ float accs[128 * 128];   // 64KB

    const int t = threadIdx.x;
    const int b = blockIdx.x;
    const int r0 = b << 7;

    float4* az = (float4*)accs;
    #pragma unroll
    for (int q = 0; q < 8; ++q)
        az[t + q * 512] = make_float4(0.f, 0.f, 0.f, 0.f);
    __syncthreads();

    const int s = bstart[b];
    const int e = bstart[b + 1];
    const int w = t >> 6;
    const int lane = t & 63;

    for (int j = s + w * 4; j < e; j += 32) {
        int nj = e - j; if (nj > 4) nj = 4;
        uint2 pe[4];
        #pragma unroll
        for (int q = 0; q < 4; ++q)
            pe[q] = (q < nj) ? bsedge[j + q] : make_uint2(0u, 0u);
        unsigned fp[4];
        #pragma unroll
        for (int q = 0; q < 4; ++q)
            fp[q] = (q < nj) ? fbfu[(size_t)(pe[q].x & 0x1FFFFu) * 64 + lane] : 0u;
        #pragma unroll
        for (int q = 0; q < 4; ++q) {
            if (q < nj) {
                float v = __uint_as_float(pe[q].y);
                int rl = pe[q].x >> 17;
                float* ap = accs + rl * 128 + lane * 2;
                atomicAdd(ap,     v * bf2f((unsigned short)(fp[q] & 0xFFFFu)));
                atomicAdd(ap + 1, v * bf2f((unsigned short)(fp[q] >> 16)));
            }
        }
    }
    __syncthreads();

    // emit: 512 thr = 16 col-groups x 32 row-slots, 4 row iterations
    const int l = t & 15, rq = t >> 4;
    #pragma unroll
    for (int it = 0; it < 4; ++it) {
        int rl = rq + it * 32;
        int row = r0 + rl;
        if (row >= N) continue;
        float4 fa = feat4[(size_t)row * 32 + 2 * l];
        float4 fb = feat4[(size_t)row * 32 + 2 * l + 1];
        float f[8] = { fa.x, fa.y, fa.z, fa.w, fb.x, fb.y, fb.z, fb.w };
        const float* hp = accs + rl * 128 + l * 8;
        ushort8_t av, mv;
        #pragma unroll
        for (int q = 0; q < 8; ++q) {
            float h = hp[q];
            av[q] = f2bf(f[q] + h);
            mv[q] = f2bf(f[q] * h);
        }
        int swz = (row & 7) << 4;
        unsigned char* rowp = ambf + (size_t)row * 512;
        *(ushort8_t*)(rowp + ((16 * l) ^ swz))       = av;
        *(ushort8_t*)(rowp + 256 + ((16 * l) ^ swz)) = mv;
    }
}

// ===========================================================================
// MFMA fused GEMM v2: stage = pure 32KB copy of pre-swizzled ambf tile.
// ===========================================================================
__global__ __launch_bounds__(256) void mfma_gemm2_kernel(
    const unsigned char* __restrict__ ambf,
    const unsigned short* __restrict__ WT,
    const float* __restrict__ b1, const float* __restrict__ b2,
    float* __restrict__ out, int N)
{
    __shared__ __align__(16) unsigned char am_raw[64 * 512];

    const int tid = threadIdx.x;
    const int block0 = blockIdx.x * BM;

    const short8* src = (const short8*)(ambf + (size_t)block0 * 512);
    short8* dst = (short8*)am_raw;
    #pragma unroll
    for (int it = 0; it < 8; ++it) {
        int idx = tid + it * 256;
        dst[idx] = src[idx];
    }
    __syncthreads();

    const int lane = tid & 63;
    const int w    = tid >> 6;
    const int wr   = w >> 1;
    const int wc   = w & 1;
    const int l15  = lane & 15;
    const int lk   = lane >> 4;
    const int rswz = (l15 & 7) << 4;

    f32x4 acc[2][4] = {};

    const char* WTc = (const char*)WT;
    const unsigned char* arow0 = am_raw + (wr * 32 + l15) * 512;
    const unsigned char* arow1 = arow0 + 16 * 512;

    #pragma unroll
    for (int ks = 0; ks < 8; ++ks) {
        int kbyte = ks * 64 + lk * 16;
        int akoff = kbyte ^ rswz;
        short8 a0 = *(const short8*)(arow0 + akoff);
        short8 a1 = *(const short8*)(arow1 + akoff);
        short8 bfr[4];
        #pragma unroll
        for (int nc = 0; nc < 4; ++nc) {
            int col = wc * 64 + nc * 16 + l15;
            bfr[nc] = *(const short8*)(WTc + col * 512 + kbyte);
        }
        #pragma unroll
        for (int nc = 0; nc < 4; ++nc) {
            acc[0][nc] = __builtin_amdgcn_mfma_f32_16x16x32_bf16(a0, bfr[nc], acc[0][nc], 0, 0, 0);
            acc[1][nc] = __builtin_amdgcn_mfma_f32_16x16x32_bf16(a1, bfr[nc], acc[1][nc], 0, 0, 0);
        }
    }

    #pragma unroll
    for (int nc = 0; nc < 4; ++nc) {
        int col = wc * 64 + nc * 16 + l15;
        float bias = b1[col] + b2[col];
        #pragma unroll
        for (int mr = 0; mr < 2; ++mr) {
            int rbase = block0 + wr * 32 + mr * 16 + lk * 4;
            #pragma unroll
            for (int r = 0; r < 4; ++r) {
                int row = rbase + r;
                if (row < N) {
                    float v = acc[mr][nc][r] + bias;
                    out[row * 128 + col] = (v >= 0.f) ? v : 0.01f * v;
                }
            }
        }
    }
}

// ===========================================================================
// Tier-2 fallback: round-3 CSR path (hist/scan/sort/spmm fp32 + mfma_gemm)
// ===========================================================================
__global__ __launch_bounds__(256) void hist_kernel(
    const int* __restrict__ rows, int* __restrict__ counts, int E)
{
    int e = blockIdx.x * 256 + threadIdx.x;
    if (e < E) atomicAdd(&counts[rows[e]], 1);
}

__global__ __launch_bounds__(256) void scan_pass1(
    const int* __restrict__ counts, int* __restrict__ btot, int N)
{
    int tid = threadIdx.x;
    int i = blockIdx.x * 1024 + tid * 4;
    int s = 0;
    if (i + 3 < N) {
        int4 v = *(const int4*)(counts + i);
        s = v.x + v.y + v.z + v.w;
    } else {
        for (int q = 0; q < 4; ++q) if (i + q < N) s += counts[i + q];
    }
    #pragma unroll
    for (int off = 32; off >= 1; off >>= 1) s += __shfl_down(s, off, 64);
    __shared__ int ws[4];
    if ((tid & 63) == 0) ws[tid >> 6] = s;
    __syncthreads();
    if (tid == 0) btot[blockIdx.x] = ws[0] + ws[1] + ws[2] + ws[3];
}

__global__ __launch_bounds__(1024) void scan_pass2(
    const int* __restrict__ btot, int* __restrict__ boff, int nb)
{
    __shared__ int wsum[16];
    int tid = threadIdx.x, lane = tid & 63, wid = tid >> 6;
    int x = (tid < nb) ? btot[tid] : 0;
    int v = x;
    #pragma unroll
    for (int off = 1; off < 64; off <<= 1) {
        int y = __shfl_up(v, off, 64);
        if (lane >= off) v += y;
    }
    if (lane == 63) wsum[wid] = v;
    __syncthreads();
    if (wid == 0 && lane < 16) {
        int s = wsum[lane];
        #pragma unroll
        for (int off = 1; off < 16; off <<= 1) {
            int y = __shfl_up(s, off, 64);
            if (lane >= off) s += y;
        }
        wsum[lane] = s;
    }
    __syncthreads();
    int wexcl = wid ? wsum[wid - 1] : 0;
    if (tid < nb) boff[tid] = wexcl + v - x;
}

__global__ __launch_bounds__(256) void scan_pass3(
    int* __restrict__ row_start, int* __restrict__ cursor,
    const int* __restrict__ boff, int N, int E)
{
    int tid = threadIdx.x;
    int base = blockIdx.x * 1024 + tid * 4;
    int c0 = 0, c1 = 0, c2 = 0, c3 = 0;
    if (base + 3 < N) {
        int4 v = *(const int4*)(row_start + base);
        c0 = v.x; c1 = v.y; c2 = v.z; c3 = v.w;
    } else {
        if (base + 0 < N) c0 = row_start[base + 0];
        if (base + 1 < N) c1 = row_start[base + 1];
        if (base + 2 < N) c2 = row_start[base + 2];
        if (base + 3 < N) c3 = row_start[base + 3];
    }
    int s0 = c0, s1 = s0 + c1, s2 = s1 + c2, s3 = s2 + c3;
    int lane = tid & 63, wid = tid >> 6;
    int v = s3;
    #pragma unroll
    for (int off = 1; off < 64; off <<= 1) {
        int y = __shfl_up(v, off, 64);
        if (lane >= off) v += y;
    }
    __shared__ int ws[4];
    if (lane == 63) ws[wid] = v;
    __syncthreads();
    int wexcl = 0;
    for (int q = 0; q < wid; ++q) wexcl += ws[q];
    int texcl = wexcl + (v - s3) + boff[blockIdx.x];
    int e0 = texcl, e1 = texcl + s0, e2 = texcl + s1, e3 = texcl + s2;
    if (base + 0 < N) { row_start[base + 0] = e0; cursor[base + 0] = e0; }
    if (base + 1 < N) { row_start[base + 1] = e1; cursor[base + 1] = e1; }
    if (base + 2 < N) { row_start[base + 2] = e2; cursor[base + 2] = e2; }
    if (base + 3 < N) { row_start[base + 3] = e3; cursor[base + 3] = e3; }
    if (blockIdx.x == 0 && tid == 0) row_start[N] = E;
}

__global__ __launch_bounds__(256) void scatter_sort_kernel(
    const int* __restrict__ rows, const int* __restrict__ cols,
    const float* __restrict__ vals, int* __restrict__ cursor,
    uint2* __restrict__ sedge, int E)
{
    int e = blockIdx.x * 256 + threadIdx.x;
    if (e < E) {
        int r = rows[e];
        int p = atomicAdd(&cursor[r], 1);
        sedge[p] = make_uint2((unsigned)cols[e], __float_as_uint(vals[e]));
    }
}

__global__ __launch_bounds__(256) void spmm_kernel(
    const float2* __restrict__ feat2,
    const int* __restrict__ row_start,
    const uint2* __restrict__ sedge,
    float2* __restrict__ h2, int N)
{
    int gw = (blockIdx.x * 256 + threadIdx.x) >> 6;
    int lane = threadIdx.x & 63;
    if (gw >= N) return;
    int s = row_start[gw];
    int e = row_start[gw + 1];
    float2 acc = make_float2(0.f, 0.f);
    int j = s;
    for (; j + 1 < e; j += 2) {
        uint2 e0 = sedge[j], e1 = sedge[j + 1];
        float v0 = __uint_as_float(e0.y), v1 = __uint_as_float(e1.y);
        float2 f0 = feat2[(size_t)e0.x * 64 + lane];
        float2 f1 = feat2[(size_t)e1.x * 64 + lane];
        acc.x = fmaf(v0, f0.x, acc.x);
        acc.y = fmaf(v0, f0.y, acc.y);
        acc.x = fmaf(v1, f1.x, acc.x);
        acc.y = fmaf(v1, f1.y, acc.y);
    }
    if (j < e) {
        uint2 e0 = sedge[j];
        float v = __uint_as_float(e0.y);
        float2 f = feat2[(size_t)e0.x * 64 + lane];
        acc.x = fmaf(v, f.x, acc.x);
        acc.y = fmaf(v, f.y, acc.y);
    }
    h2[(size_t)gw * 64 + lane] = acc;
}

__global__ __launch_bounds__(256) void mfma_gemm_kernel(
    const float4* __restrict__ feat4, const float4* __restrict__ h4,
    const unsigned short* __restrict__ WT,
    const float* __restrict__ b1, const float* __restrict__ b2,
    float* __restrict__ out, int N)
{
    __shared__ __align__(16) unsigned char am_raw[64 * 512];
    const int tid = threadIdx.x;
    const int block0 = blockIdx.x * BM;
    #pragma unroll
    for (int it = 0; it < 8; ++it) {
        int idx  = tid + it * 256;
        int node = idx >> 5;
        int p    = idx & 31;
        int g    = block0 + node;
        float4 fv = make_float4(0.f, 0.f, 0.f, 0.f);
        float4 hv = make_float4(0.f, 0.f, 0.f, 0.f);
        if (g < N) { fv = feat4[g * 32 + p]; hv = h4[g * 32 + p]; }
        ushort4 av = make_ushort4(f2bf(fv.x + hv.x), f2bf(fv.y + hv.y),
                                  f2bf(fv.z + hv.z), f2bf(fv.w + hv.w));
        ushort4 mv = make_ushort4(f2bf(fv.x * hv.x), f2bf(fv.y * hv.y),
                                  f2bf(fv.z * hv.z), f2bf(fv.w * hv.w));
        int swz = (node & 7) << 4;
        *(ushort4*)(am_raw + node * 512 + ((p * 8) ^ swz))       = av;
        *(ushort4*)(am_raw + node * 512 + ((256 + p * 8) ^ swz)) = mv;
    }
    __syncthreads();
    const int lane = tid & 63;
    const int w    = tid >> 6;
    const int wr   = w >> 1;
    const int wc   = w & 1;
    const int l15  = lane & 15;
    const int lk   = lane >> 4;
    const int rswz = (l15 & 7) << 4;
    f32x4 acc[2][4] = {};
    const char* WTc = (const char*)WT;
    const unsigned char* arow0 = am_raw + (wr * 32 + l15) * 512;
    const unsigned char* arow1 = arow0 + 16 * 512;
    #pragma unroll
    for (int ks = 0; ks < 8; ++ks) {
        int kbyte = ks * 64 + lk * 16;
        int akoff = kbyte ^ rswz;
        short8 a0 = *(const short8*)(arow0 + akoff);
        short8 a1 = *(const short8*)(arow1 + akoff);
        short8 bfr[4];
        #pragma unroll
        for (int nc = 0; nc < 4; ++nc) {
            int col = wc * 64 + nc * 16 + l15;
            bfr[nc] = *(const short8*)(WTc + col * 512 + kbyte);
        }
        #pragma unroll
        for (int nc = 0; nc < 4; ++nc) {
            acc[0][nc] = __builtin_amdgcn_mfma_f32_16x16x32_bf16(a0, bfr[nc], acc[0][nc], 0, 0, 0);
            acc[1][nc] = __builtin_amdgcn_mfma_f32_16x16x32_bf16(a1, bfr[nc], acc[1][nc], 0, 0, 0);
        }
    }
    #pragma unroll
    for (int nc = 0; nc < 4; ++nc) {
        int col = wc * 64 + nc * 16 + l15;
        float bias = b1[col] + b2[col];
        #pragma unroll
        for (int mr = 0; mr < 2; ++mr) {
            int rbase = block0 + wr * 32 + mr * 16 + lk * 4;
            #pragma unroll
            for (int r = 0; r < 4; ++r) {
                int row = rbase + r;
                if (row < N) {
                    float v = acc[mr][nc][r] + bias;
                    out[row * 128 + col] = (v >= 0.f) ? v : 0.01f * v;
                }
            }
        }
    }
}

// ===========================================================================
// Tier-3 fallback: atomic scatter + fp32 VALU GEMM
// ===========================================================================
__global__ __launch_bounds__(256) void edge_scatter_kernel(
    const float4* __restrict__ feat4, const int* __restrict__ rows,
    const int* __restrict__ cols, const float* __restrict__ vals,
    float* __restrict__ h, int E)
{
    int idx = blockIdx.x * 256 + threadIdx.x;
    if (idx >= E * 32) return;
    int e = idx >> 5;
    int p = idx & 31;
    int r = rows[e];
    int c = cols[e];
    float v = vals[e];
    float4 f = feat4[c * 32 + p];
    float* hr = h + (long long)r * D + p * 4;
    unsafeAtomicAdd(hr + 0, v * f.x);
    unsafeAtomicAdd(hr + 1, v * f.y);
    unsafeAtomicAdd(hr + 2, v * f.z);
    unsafeAtomicAdd(hr + 3, v * f.w);
}

__global__ __launch_bounds__(256) void fused_gemm_kernel(
    const float* __restrict__ feat, const float* __restrict__ h,
    const float* __restrict__ W1, const float* __restrict__ b1,
    const float* __restrict__ W2, const float* __restrict__ b2,
    float* __restrict__ out, int N)
{
    __shared__ float a_lds[BM][D];
    __shared__ float m_lds[BM][D];
    const int tid = threadIdx.x;
    const int block0 = blockIdx.x * BM;
    const float4* feat4 = (const float4*)feat;
    const float4* h4    = (const float4*)h;
    #pragma unroll
    for (int it = 0; it < 8; ++it) {
        int idx  = tid + it * 256;
        int node = idx >> 5;
        int p    = idx & 31;
        int gnode = block0 + node;
        float4 fv = make_float4(0.f, 0.f, 0.f, 0.f);
        float4 hv = make_float4(0.f, 0.f, 0.f, 0.f);
        if (gnode < N) { fv = feat4[gnode * 32 + p]; hv = h4[gnode * 32 + p]; }
        float4 av = make_float4(fv.x + hv.x, fv.y + hv.y, fv.z + hv.z, fv.w + hv.w);
        float4 mv = make_float4(fv.x * hv.x, fv.y * hv.y, fv.z * hv.z, fv.w * hv.w);
        *(float4*)&a_lds[node][p * 4] = av;
        *(float4*)&m_lds[node][p * 4] = mv;
    }
    __syncthreads();
    const int c = tid & 31;
    const int g = tid >> 5;
    float acc[8][4] = {};
    const float4* W1v = (const float4*)W1;
    const float4* W2v = (const float4*)W2;
    for (int k = 0; k < D; ++k) {
        float4 w1 = W1v[k * 32 + c];
        float4 w2 = W2v[k * 32 + c];
        #pragma unroll
        for (int t = 0; t < 8; ++t) {
            float av = a_lds[g + 8 * t][k];
            float mv = m_lds[g + 8 * t][k];
            acc[t][0] = fmaf(av, w1.x, fmaf(mv, w2.x, acc[t][0]));
            acc[t][1] = fmaf(av, w1.y, fmaf(mv, w2.y, acc[t][1]));
            acc[t][2] = fmaf(av, w1.z, fmaf(mv, w2.z, acc[t][2]));
            acc[t][3] = fmaf(av, w1.w, fmaf(mv, w2.w, acc[t][3]));
        }
    }
    float4 bb1 = ((const float4*)b1)[c];
    float4 bb2 = ((const float4*)b2)[c];
    const float bx = bb1.x + bb2.x, by = bb1.y + bb2.y;
    const float bz = bb1.z + bb2.z, bw = bb1.w + bb2.w;
    #pragma unroll
    for (int t = 0; t < 8; ++t) {
        int gnode = block0 + g + 8 * t;
        if (gnode >= N) continue;
        float4 o;
        o.x = acc[t][0] + bx; o.y = acc[t][1] + by;
        o.z = acc[t][2] + bz; o.w = acc[t][3] + bw;
        o.x = (o.x >= 0.f) ? o.x : 0.01f * o.x;
        o.y = (o.y >= 0.f) ? o.y : 0.01f * o.y;
        o.z = (o.z >= 0.f) ? o.z : 0.01f * o.z;
        o.w = (o.w >= 0.f) ? o.w : 0.01f * o.w;
        ((float4*)out)[gnode * 32 + c] = o;
    }
}

extern "C" void kernel_launch(void* const* d_in, const int* in_sizes, int n_in,
                              void* d_out, int out_size, void* d_ws, size_t ws_size,
                              hipStream_t stream) {
    const float* feat = (const float*)d_in[0];
    const int*   rows = (const int*)d_in[1];
    const int*   cols = (const int*)d_in[2];
    const float* vals = (const float*)d_in[3];
    const float* W1   = (const float*)d_in[4];
    const float* b1   = (const float*)d_in[5];
    const float* W2   = (const float*)d_in[6];
    const float* b2   = (const float*)d_in[7];

    const int N = in_sizes[0] / D;
    const int E = in_sizes[1];
    float* out = (float*)d_out;

    const int NBK  = (N + 127) >> 7;          // 128-row buckets (782)
    const int Npad = NBK << 7;                // ambf row padding for gemm stage

    // --- Tier-1 ws layout: ambf | featbf | bsedge | WT | bcnt | bstart | bcur
    size_t off = 0;
    unsigned char* ambf = (unsigned char*)d_ws;              off += (size_t)Npad * 512;
    unsigned short* featbf = (unsigned short*)((char*)d_ws + off); off += (size_t)N * D * 2;
    off = (off + 15) & ~(size_t)15;
    uint2* bsedge = (uint2*)((char*)d_ws + off);             off += (size_t)E * 8;
    unsigned short* WT = (unsigned short*)((char*)d_ws + off); off += 128 * 256 * 2;
    int* bcnt   = (int*)((char*)d_ws + off);                 off += (size_t)NBK * 4;
    int* bstart = (int*)((char*)d_ws + off);                 off += (size_t)(NBK + 1) * 4;
    int* bcur   = (int*)((char*)d_ws + off);                 off += (size_t)NBK * 4;
    size_t need1 = off;

    if (ws_size >= need1 && NBK <= 1024 && N <= (1 << 17)) {
        hipMemsetAsync(bcnt, 0, (size_t)NBK * sizeof(int), stream);
        fconv_kernel<<<(N * 32 + 255) / 256, 256, 0, stream>>>(
            (const float4*)feat, (ushort4*)featbf, N * 32);
        wconv_kernel<<<128, 256, 0, stream>>>(W1, W2, WT);
        int epb = (E + 255) / 256;
        bucket_hist_kernel<<<256, 256, 0, stream>>>(rows, bcnt, E, NBK, epb);
        bucket_scan_kernel<<<1, 1024, 0, stream>>>(bcnt, bstart, bcur, NBK, E);
        bucket_scatter_kernel<<<(E + 4095) / 4096, 256, 0, stream>>>(
            rows, cols, vals, bcur, bsedge, E, NBK);
        spmm_bucket_kernel<<<NBK, 512, 0, stream>>>(
            (const float4*)feat, (const unsigned*)featbf, bstart, bsedge, ambf, N);
        mfma_gemm2_kernel<<<(N + BM - 1) / BM, 256, 0, stream>>>(
            ambf, WT, b1, b2, out, N);
        return;
    }

    // --- Tier-2 ws layout: h | row_start | cursor | sedge | WT | btot | boff
    const int NB = (N + 1023) / 1024;
    off = 0;
    float* h = (float*)d_ws;                           off += (size_t)N * D * 4;
    int* row_start = (int*)((char*)d_ws + off);        off += (size_t)(N + 1) * 4;
    int* cursor    = (int*)((char*)d_ws + off);        off += (size_t)N * 4;
    off = (off + 15) & ~(size_t)15;
    uint2* sedge   = (uint2*)((char*)d_ws + off);      off += (size_t)E * 8;
    off = (off + 15) & ~(size_t)15;
    WT = (unsigned short*)((char*)d_ws + off);         off += 128 * 256 * 2;
    int* btot = (int*)((char*)d_ws + off);             off += (size_t)NB * 4;
    int* boff = (int*)((char*)d_ws + off);             off += (size_t)NB * 4;
    size_t need2 = off;

    if (ws_size >= need2 && NB <= 1024) {
        hipMemsetAsync(row_start, 0, (size_t)(N + 1) * sizeof(int), stream);
        wconv_kernel<<<128, 256, 0, stream>>>(W1, W2, WT);
        hist_kernel<<<(E + 255) / 256, 256, 0, stream>>>(rows, row_start, E);
        scan_pass1<<<NB, 256, 0, stream>>>(row_start, btot, N);
        scan_pass2<<<1, 1024, 0, stream>>>(btot, boff, NB);
        scan_pass3<<<NB, 256, 0, stream>>>(row_start, cursor, boff, N, E);
        scatter_sort_kernel<<<(E + 255) / 256, 256, 0, stream>>>(
            rows, cols, vals, cursor, sedge, E);
        spmm_kernel<<<(N * 64 + 255) / 256, 256, 0, stream>>>(
            (const float2*)feat, row_start, sedge, (float2*)h, N);
        mfma_gemm_kernel<<<(N + BM - 1) / BM, 256, 0, stream>>>(
            (const float4*)feat, (const float4*)h, WT, b1, b2, out, N);
        return;
    }

    // --- Tier-3: atomic scatter + VALU GEMM
    size_t hbytes = (size_t)N * D * sizeof(float);
    float* hh = (ws_size >= hbytes) ? (float*)d_ws : out;
    hipMemsetAsync(hh, 0, hbytes, stream);
    edge_scatter_kernel<<<((size_t)E * 32 + 255) / 256, 256, 0, stream>>>(
        (const float4*)feat, rows, cols, vals, hh, E);
    fused_gemm_kernel<<<(N + BM - 1) / BM, 256, 0, stream>>>(
        feat, hh, W1, b1, W2, b2, out, N);
}

// Round 6
// 200.432 us; speedup vs baseline: 7.1896x; 7.1896x over previous
//
#include <hip/hip_runtime.h>

#define D 128
#define BM 64

typedef short short8 __attribute__((ext_vector_type(8)));
typedef unsigned short ushort8_t __attribute__((ext_vector_type(8)));
typedef float f32x4 __attribute__((ext_vector_type(4)));

__device__ __forceinline__ unsigned short f2bf(float x) {
    unsigned u = __float_as_uint(x);
    unsigned r = (u + 0x7fffu + ((u >> 16) & 1u)) >> 16;   // RNE
    return (unsigned short)r;
}
__device__ __forceinline__ float bf2f(unsigned short u) {
    return __uint_as_float(((unsigned)u) << 16);
}

// ===========================================================================
// features fp32 -> bf16 (linear layout)
// ===========================================================================
__global__ __launch_bounds__(256) void fconv_kernel(
    const float4* __restrict__ feat4, ushort4* __restrict__ fbf4, int total)
{
    int i = blockIdx.x * 256 + threadIdx.x;
    if (i < total) {
        float4 v = feat4[i];
        fbf4[i] = make_ushort4(f2bf(v.x), f2bf(v.y), f2bf(v.z), f2bf(v.w));
    }
}

// ===========================================================================
// W -> WT bf16: WT[c][k] = (k<128 ? W1[k][c] : W2[k-128][c]), [128][256]
// ===========================================================================
__global__ __launch_bounds__(256) void wconv_kernel(
    const float* __restrict__ W1, const float* __restrict__ W2,
    unsigned short* __restrict__ WT)
{
    int idx = blockIdx.x * 256 + threadIdx.x;   // 32768
    int c = idx & 127;
    int k = idx >> 7;
    float w = (k < 128) ? W1[k * 128 + c] : W2[(k - 128) * 128 + c];
    WT[c * 256 + k] = f2bf(w);
}

// ===========================================================================
// Bucket CSR build (tier-1a): hist -> scan -> grouped scatter -> local sort.
// Buckets are 128 rows; edge key = (r&127)<<17 | col (needs N <= 2^17).
// ===========================================================================

__global__ __launch_bounds__(256) void bucket_hist_kernel(
    const int* __restrict__ rows, int* __restrict__ bcnt, int E, int nb, int epb)
{
    __shared__ int cnt[1024];
    int t = threadIdx.x;
    for (int i = t; i < nb; i += 256) cnt[i] = 0;
    __syncthreads();
    int e0 = blockIdx.x * epb;
    int e1 = e0 + epb; if (e1 > E) e1 = E;
    for (int e = e0 + t; e < e1; e += 256) atomicAdd(&cnt[rows[e] >> 7], 1);
    __syncthreads();
    for (int i = t; i < nb; i += 256)
        if (cnt[i]) atomicAdd(&bcnt[i], cnt[i]);
}

__global__ __launch_bounds__(1024) void bucket_scan_kernel(
    const int* __restrict__ bcnt, int* __restrict__ bstart,
    int* __restrict__ bcur, int nb, int E)
{
    __shared__ int wsum[16];
    int tid = threadIdx.x, lane = tid & 63, wid = tid >> 6;
    int x = (tid < nb) ? bcnt[tid] : 0;
    int v = x;
    #pragma unroll
    for (int off = 1; off < 64; off <<= 1) {
        int y = __shfl_up(v, off, 64);
        if (lane >= off) v += y;
    }
    if (lane == 63) wsum[wid] = v;
    __syncthreads();
    if (wid == 0 && lane < 16) {
        int s = wsum[lane];
        #pragma unroll
        for (int off = 1; off < 16; off <<= 1) {
            int y = __shfl_up(s, off, 64);
            if (lane >= off) s += y;
        }
        wsum[lane] = s;
    }
    __syncthreads();
    int wexcl = wid ? wsum[wid - 1] : 0;
    int excl = wexcl + v - x;
    if (tid < nb) { bstart[tid] = excl; bcur[tid] = excl; }
    if (tid == 0) bstart[nb] = E;
}

// 4096 edges/block: LDS hist -> reserve contiguous run per bucket -> write runs.
__global__ __launch_bounds__(256) void bucket_scatter_kernel(
    const int* __restrict__ rows, const int* __restrict__ cols,
    const float* __restrict__ vals, int* __restrict__ bcur,
    uint2* __restrict__ bsedge, int E, int nb)
{
    __shared__ int cnt[1024];
    __shared__ int base[1024];
    int t = threadIdx.x;
    int e0 = blockIdx.x * 4096;
    for (int i = t; i < nb; i += 256) cnt[i] = 0;
    __syncthreads();
    #pragma unroll
    for (int q = 0; q < 16; ++q) {
        int e = e0 + t + q * 256;
        if (e < E) atomicAdd(&cnt[rows[e] >> 7], 1);
    }
    __syncthreads();
    for (int i = t; i < nb; i += 256) {
        int c = cnt[i];
        if (c) { base[i] = atomicAdd(&bcur[i], c); cnt[i] = 0; }
    }
    __syncthreads();
    #pragma unroll
    for (int q = 0; q < 16; ++q) {
        int e = e0 + t + q * 256;
        if (e < E) {
            int r = rows[e];
            int b = r >> 7;
            int pos = base[b] + atomicAdd(&cnt[b], 1);
            bsedge[pos] = make_uint2(((unsigned)(r & 127) << 17) | (unsigned)cols[e],
                                     __float_as_uint(vals[e]));
        }
    }
}

// One block per bucket: LDS hist(128) + 1-wave pair scan + LDS-cursor scatter.
// Output writes are random only within the bucket's ~16KB window (L2-local).
// Emits row_start (global CSR offsets) as a by-product.
__global__ __launch_bounds__(256) void bucket_sort_kernel(
    const uint2* __restrict__ bsedge,
    const int* __restrict__ bstart,
    uint2* __restrict__ sedge,
    int* __restrict__ row_start,
    int N, int E)
{
    __shared__ int cnt[128];
    __shared__ int base[128];
    const int b = blockIdx.x;
    const int t = threadIdx.x;
    const int s = bstart[b], e = bstart[b + 1];
    if (t < 128) cnt[t] = 0;
    __syncthreads();
    for (int j = s + t; j < e; j += 256)
        atomicAdd(&cnt[bsedge[j].x >> 17], 1);
    __syncthreads();
    if (t < 64) {
        int c0 = cnt[2 * t], c1 = cnt[2 * t + 1];
        int pair = c0 + c1;
        int v = pair;
        #pragma unroll
        for (int off = 1; off < 64; off <<= 1) {
            int y = __shfl_up(v, off, 64);
            if (t >= off) v += y;
        }
        int excl = v - pair;                 // exclusive over pairs
        base[2 * t]     = excl;
        base[2 * t + 1] = excl + c0;
        cnt[2 * t] = 0;
        cnt[2 * t + 1] = 0;                  // reuse as cursors
    }
    __syncthreads();
    const int r0 = b << 7;
    if (t < 128 && r0 + t < N) row_start[r0 + t] = s + base[t];
    if (b == 0 && t == 0) row_start[N] = E;
    for (int j = s + t; j < e; j += 256) {
        uint2 ed = bsedge[j];
        int rl = ed.x >> 17;
        int p = atomicAdd(&cnt[rl], 1);
        sedge[s + base[rl] + p] = make_uint2(ed.x & 0x1FFFFu, ed.y);
    }
}

// ===========================================================================
// SpMM + A/M build (round-4, proven): 4 rows/wave, 16 lanes x 16B bf16 gather.
// Writes a=(f+h), m=(f*h) bf16 into ambf[row][512B], pre-swizzled for GEMM.
// ===========================================================================
__global__ __launch_bounds__(256) void spmm_ab_kernel(
    const float4* __restrict__ feat4,
    const ushort8_t* __restrict__ fbf8,
    const int* __restrict__ row_start,
    const uint2* __restrict__ sedge,
    unsigned char* __restrict__ ambf, int N)
{
    int t = blockIdx.x * 256 + threadIdx.x;
    int row = t >> 4;
    int l   = t & 15;
    if (row >= N) return;

    int s = row_start[row];
    int e = row_start[row + 1];

    float acc[8] = {};
    int j = s;
    for (; j + 1 < e; j += 2) {
        uint2 e0 = sedge[j], e1 = sedge[j + 1];
        float v0 = __uint_as_float(e0.y), v1 = __uint_as_float(e1.y);
        ushort8_t f0 = fbf8[(size_t)e0.x * 16 + l];
        ushort8_t f1 = fbf8[(size_t)e1.x * 16 + l];
        #pragma unroll
        for (int q = 0; q < 8; ++q) {
            acc[q] = fmaf(v0, bf2f(f0[q]), acc[q]);
            acc[q] = fmaf(v1, bf2f(f1[q]), acc[q]);
        }
    }
    if (j < e) {
        uint2 e0 = sedge[j];
        float v = __uint_as_float(e0.y);
        ushort8_t f = fbf8[(size_t)e0.x * 16 + l];
        #pragma unroll
        for (int q = 0; q < 8; ++q) acc[q] = fmaf(v, bf2f(f[q]), acc[q]);
    }

    float4 fa = feat4[(size_t)row * 32 + 2 * l];
    float4 fb = feat4[(size_t)row * 32 + 2 * l + 1];
    float f[8] = { fa.x, fa.y, fa.z, fa.w, fb.x, fb.y, fb.z, fb.w };

    ushort8_t av, mv;
    #pragma unroll
    for (int q = 0; q < 8; ++q) {
        av[q] = f2bf(f[q] + acc[q]);
        mv[q] = f2bf(f[q] * acc[q]);
    }

    int swz = (row & 7) << 4;
    unsigned char* rowp = ambf + (size_t)row * 512;
    *(ushort8_t*)(rowp + ((16 * l) ^ swz))       = av;
    *(ushort8_t*)(rowp + 256 + ((16 * l) ^ swz)) = mv;
}

// ===========================================================================
// MFMA fused GEMM v2 (round-4, proven): stage = 32KB linear copy of ambf.
// ===========================================================================
__global__ __launch_bounds__(256) void mfma_gemm2_kernel(
    const unsigned char* __restrict__ ambf,
    const unsigned short* __restrict__ WT,
    const float* __restrict__ b1, const float* __restrict__ b2,
    float* __restrict__ out, int N)
{
    __shared__ __align__(16) unsigned char am_raw[64 * 512];

    const int tid = threadIdx.x;
    const int block0 = blockIdx.x * BM;

    const short8* src = (const short8*)(ambf + (size_t)block0 * 512);
    short8* dst = (short8*)am_raw;
    #pragma unroll
    for (int it = 0; it < 8; ++it) {
        int idx = tid + it * 256;
        dst[idx] = src[idx];
    }
    __syncthreads();

    const int lane = tid & 63;
    const int w    = tid >> 6;
    const int wr   = w >> 1;
    const int wc   = w & 1;
    const int l15  = lane & 15;
    const int lk   = lane >> 4;
    const int rswz = (l15 & 7) << 4;

    f32x4 acc[2][4] = {};

    const char* WTc = (const char*)WT;
    const unsigned char* arow0 = am_raw + (wr * 32 + l15) * 512;
    const unsigned char* arow1 = arow0 + 16 * 512;

    #pragma unroll
    for (int ks = 0; ks < 8; ++ks) {
        int kbyte = ks * 64 + lk * 16;
        int akoff = kbyte ^ rswz;
        short8 a0 = *(const short8*)(arow0 + akoff);
        short8 a1 = *(const short8*)(arow1 + akoff);
        short8 bfr[4];
        #pragma unroll
        for (int nc = 0; nc < 4; ++nc) {
            int col = wc * 64 + nc * 16 + l15;
            bfr[nc] = *(const short8*)(WTc + col * 512 + kbyte);
        }
        #pragma unroll
        for (int nc = 0; nc < 4; ++nc) {
            acc[0][nc] = __builtin_amdgcn_mfma_f32_16x16x32_bf16(a0, bfr[nc], acc[0][nc], 0, 0, 0);
            acc[1][nc] = __builtin_amdgcn_mfma_f32_16x16x32_bf16(a1, bfr[nc], acc[1][nc], 0, 0, 0);
        }
    }

    #pragma unroll
    for (int nc = 0; nc < 4; ++nc) {
        int col = wc * 64 + nc * 16 + l15;
        float bias = b1[col] + b2[col];
        #pragma unroll
        for (int mr = 0; mr < 2; ++mr) {
            int rbase = block0 + wr * 32 + mr * 16 + lk * 4;
            #pragma unroll
            for (int r = 0; r < 4; ++r) {
                int row = rbase + r;
                if (row < N) {
                    float v = acc[mr][nc][r] + bias;
                    out[row * 128 + col] = (v >= 0.f) ? v : 0.01f * v;
                }
            }
        }
    }
}

// ===========================================================================
// Tier-1b/2 CSR kernels (round-3/4, proven)
// ===========================================================================
__global__ __launch_bounds__(256) void hist_kernel(
    const int* __restrict__ rows, int* __restrict__ counts, int E)
{
    int e = blockIdx.x * 256 + threadIdx.x;
    if (e < E) atomicAdd(&counts[rows[e]], 1);
}

__global__ __launch_bounds__(256) void scan_pass1(
    const int* __restrict__ counts, int* __restrict__ btot, int N)
{
    int tid = threadIdx.x;
    int i = blockIdx.x * 1024 + tid * 4;
    int s = 0;
    if (i + 3 < N) {
        int4 v = *(const int4*)(counts + i);
        s = v.x + v.y + v.z + v.w;
    } else {
        for (int q = 0; q < 4; ++q) if (i + q < N) s += counts[i + q];
    }
    #pragma unroll
    for (int off = 32; off >= 1; off >>= 1) s += __shfl_down(s, off, 64);
    __shared__ int ws[4];
    if ((tid & 63) == 0) ws[tid >> 6] = s;
    __syncthreads();
    if (tid == 0) btot[blockIdx.x] = ws[0] + ws[1] + ws[2] + ws[3];
}

__global__ __launch_bounds__(1024) void scan_pass2(
    const int* __restrict__ btot, int* __restrict__ boff, int nb)
{
    __shared__ int wsum[16];
    int tid = threadIdx.x, lane = tid & 63, wid = tid >> 6;
    int x = (tid < nb) ? btot[tid] : 0;
    int v = x;
    #pragma unroll
    for (int off = 1; off < 64; off <<= 1) {
        int y = __shfl_up(v, off, 64);
        if (lane >= off) v += y;
    }
    if (lane == 63) wsum[wid] = v;
    __syncthreads();
    if (wid == 0 && lane < 16) {
        int s = wsum[lane];
        #pragma unroll
        for (int off = 1; off < 16; off <<= 1) {
            int y = __shfl_up(s, off, 64);
            if (lane >= off) s += y;
        }
        wsum[lane] = s;
    }
    __syncthreads();
    int wexcl = wid ? wsum[wid - 1] : 0;
    if (tid < nb) boff[tid] = wexcl + v - x;
}

__global__ __launch_bounds__(256) void scan_pass3(
    int* __restrict__ row_start, int* __restrict__ cursor,
    const int* __restrict__ boff, int N, int E)
{
    int tid = threadIdx.x;
    int base = blockIdx.x * 1024 + tid * 4;
    int c0 = 0, c1 = 0, c2 = 0, c3 = 0;
    if (base + 3 < N) {
        int4 v = *(const int4*)(row_start + base);
        c0 = v.x; c1 = v.y; c2 = v.z; c3 = v.w;
    } else {
        if (base + 0 < N) c0 = row_start[base + 0];
        if (base + 1 < N) c1 = row_start[base + 1];
        if (base + 2 < N) c2 = row_start[base + 2];
        if (base + 3 < N) c3 = row_start[base + 3];
    }
    int s0 = c0, s1 = s0 + c1, s2 = s1 + c2, s3 = s2 + c3;
    int lane = tid & 63, wid = tid >> 6;
    int v = s3;
    #pragma unroll
    for (int off = 1; off < 64; off <<= 1) {
        int y = __shfl_up(v, off, 64);
        if (lane >= off) v += y;
    }
    __shared__ int ws[4];
    if (lane == 63) ws[wid] = v;
    __syncthreads();
    int wexcl = 0;
    for (int q = 0; q < wid; ++q) wexcl += ws[q];
    int texcl = wexcl + (v - s3) + boff[blockIdx.x];
    int e0 = texcl, e1 = texcl + s0, e2 = texcl + s1, e3 = texcl + s2;
    if (base + 0 < N) { row_start[base + 0] = e0; cursor[base + 0] = e0; }
    if (base + 1 < N) { row_start[base + 1] = e1; cursor[base + 1] = e1; }
    if (base + 2 < N) { row_start[base + 2] = e2; cursor[base + 2] = e2; }
    if (base + 3 < N) { row_start[base + 3] = e3; cursor[base + 3] = e3; }
    if (blockIdx.x == 0 && tid == 0) row_start[N] = E;
}

__global__ __launch_bounds__(256) void scatter_sort_kernel(
    const int* __restrict__ rows, const int* __restrict__ cols,
    const float* __restrict__ vals, int* __restrict__ cursor,
    uint2* __restrict__ sedge, int E)
{
    int e = blockIdx.x * 256 + threadIdx.x;
    if (e < E) {
        int r = rows[e];
        int p = atomicAdd(&cursor[r], 1);
        sedge[p] = make_uint2((unsigned)cols[e], __float_as_uint(vals[e]));
    }
}

__global__ __launch_bounds__(256) void spmm_kernel(
    const float2* __restrict__ feat2,
    const int* __restrict__ row_start,
    const uint2* __restrict__ sedge,
    float2* __restrict__ h2, int N)
{
    int gw = (blockIdx.x * 256 + threadIdx.x) >> 6;
    int lane = threadIdx.x & 63;
    if (gw >= N) return;
    int s = row_start[gw];
    int e = row_start[gw + 1];
    float2 acc = make_float2(0.f, 0.f);
    int j = s;
    for (; j + 1 < e; j += 2) {
        uint2 e0 = sedge[j], e1 = sedge[j + 1];
        float v0 = __uint_as_float(e0.y), v1 = __uint_as_float(e1.y);
        float2 f0 = feat2[(size_t)e0.x * 64 + lane];
        float2 f1 = feat2[(size_t)e1.x * 64 + lane];
        acc.x = fmaf(v0, f0.x, acc.x);
        acc.y = fmaf(v0, f0.y, acc.y);
        acc.x = fmaf(v1, f1.x, acc.x);
        acc.y = fmaf(v1, f1.y, acc.y);
    }
    if (j < e) {
        uint2 e0 = sedge[j];
        float v = __uint_as_float(e0.y);
        float2 f = feat2[(size_t)e0.x * 64 + lane];
        acc.x = fmaf(v, f.x, acc.x);
        acc.y = fmaf(v, f.y, acc.y);
    }
    h2[(size_t)gw * 64 + lane] = acc;
}

__global__ __launch_bounds__(256) void mfma_gemm_kernel(
    const float4* __restrict__ feat4, const float4* __restrict__ h4,
    const unsigned short* __restrict__ WT,
    const float* __restrict__ b1, const float* __restrict__ b2,
    float* __restrict__ out, int N)
{
    __shared__ __align__(16) unsigned char am_raw[64 * 512];
    const int tid = threadIdx.x;
    const int block0 = blockIdx.x * BM;
    #pragma unroll
    for (int it = 0; it < 8; ++it) {
        int idx  = tid + it * 256;
        int node = idx >> 5;
        int p    = idx & 31;
        int g    = block0 + node;
        float4 fv = make_float4(0.f, 0.f, 0.f, 0.f);
        float4 hv = make_float4(0.f, 0.f, 0.f, 0.f);
        if (g < N) { fv = feat4[g * 32 + p]; hv = h4[g * 32 + p]; }
        ushort4 av = make_ushort4(f2bf(fv.x + hv.x), f2bf(fv.y + hv.y),
                                  f2bf(fv.z + hv.z), f2bf(fv.w + hv.w));
        ushort4 mv = make_ushort4(f2bf(fv.x * hv.x), f2bf(fv.y * hv.y),
                                  f2bf(fv.z * hv.z), f2bf(fv.w * hv.w));
        int swz = (node & 7) << 4;
        *(ushort4*)(am_raw + node * 512 + ((p * 8) ^ swz))       = av;
        *(ushort4*)(am_raw + node * 512 + ((256 + p * 8) ^ swz)) = mv;
    }
    __syncthreads();
    const int lane = tid & 63;
    const int w    = tid >> 6;
    const int wr   = w >> 1;
    const int wc   = w & 1;
    const int l15  = lane & 15;
    const int lk   = lane >> 4;
    const int rswz = (l15 & 7) << 4;
    f32x4 acc[2][4] = {};
    const char* WTc = (const char*)WT;
    const unsigned char* arow0 = am_raw + (wr * 32 + l15) * 512;
    const unsigned char* arow1 = arow0 + 16 * 512;
    #pragma unroll
    for (int ks = 0; ks < 8; ++ks) {
        int kbyte = ks * 64 + lk * 16;
        int akoff = kbyte ^ rswz;
        short8 a0 = *(const short8*)(arow0 + akoff);
        short8 a1 = *(const short8*)(arow1 + akoff);
        short8 bfr[4];
        #pragma unroll
        for (int nc = 0; nc < 4; ++nc) {
            int col = wc * 64 + nc * 16 + l15;
            bfr[nc] = *(const short8*)(WTc + col * 512 + kbyte);
        }
        #pragma unroll
        for (int nc = 0; nc < 4; ++nc) {
            acc[0][nc] = __builtin_amdgcn_mfma_f32_16x16x32_bf16(a0, bfr[nc], acc[0][nc], 0, 0, 0);
            acc[1][nc] = __builtin_amdgcn_mfma_f32_16x16x32_bf16(a1, bfr[nc], acc[1][nc], 0, 0, 0);
        }
    }
    #pragma unroll
    for (int nc = 0; nc < 4; ++nc) {
        int col = wc * 64 + nc * 16 + l15;
        float bias = b1[col] + b2[col];
        #pragma unroll
        for (int mr = 0; mr < 2; ++mr) {
            int rbase = block0 + wr * 32 + mr * 16 + lk * 4;
            #pragma unroll
            for (int r = 0; r < 4; ++r) {
                int row = rbase + r;
                if (row < N) {
                    float v = acc[mr][nc][r] + bias;
                    out[row * 128 + col] = (v >= 0.f) ? v : 0.01f * v;
                }
            }
        }
    }
}

// ===========================================================================
// Tier-3: atomic scatter + fp32 VALU GEMM
// ===========================================================================
__global__ __launch_bounds__(256) void edge_scatter_kernel(
    const float4* __restrict__ feat4, const int* __restrict__ rows,
    const int* __restrict__ cols, const float* __restrict__ vals,
    float* __restrict__ h, int E)
{
    int idx = blockIdx.x * 256 + threadIdx.x;
    if (idx >= E * 32) return;
    int e = idx >> 5;
    int p = idx & 31;
    int r = rows[e];
    int c = cols[e];
    float v = vals[e];
    float4 f = feat4[c * 32 + p];
    float* hr = h + (long long)r * D + p * 4;
    unsafeAtomicAdd(hr + 0, v * f.x);
    unsafeAtomicAdd(hr + 1, v * f.y);
    unsafeAtomicAdd(hr + 2, v * f.z);
    unsafeAtomicAdd(hr + 3, v * f.w);
}

__global__ __launch_bounds__(256) void fused_gemm_kernel(
    const float* __restrict__ feat, const float* __restrict__ h,
    const float* __restrict__ W1, const float* __restrict__ b1,
    const float* __restrict__ W2, const float* __restrict__ b2,
    float* __restrict__ out, int N)
{
    __shared__ float a_lds[BM][D];
    __shared__ float m_lds[BM][D];
    const int tid = threadIdx.x;
    const int block0 = blockIdx.x * BM;
    const float4* feat4 = (const float4*)feat;
    const float4* h4    = (const float4*)h;
    #pragma unroll
    for (int it = 0; it < 8; ++it) {
        int idx  = tid + it * 256;
        int node = idx >> 5;
        int p    = idx & 31;
        int gnode = block0 + node;
        float4 fv = make_float4(0.f, 0.f, 0.f, 0.f);
        float4 hv = make_float4(0.f, 0.f, 0.f, 0.f);
        if (gnode < N) { fv = feat4[gnode * 32 + p]; hv = h4[gnode * 32 + p]; }
        float4 av = make_float4(fv.x + hv.x, fv.y + hv.y, fv.z + hv.z, fv.w + hv.w);
        float4 mv = make_float4(fv.x * hv.x, fv.y * hv.y, fv.z * hv.z, fv.w * hv.w);
        *(float4*)&a_lds[node][p * 4] = av;
        *(float4*)&m_lds[node][p * 4] = mv;
    }
    __syncthreads();
    const int c = tid & 31;
    const int g = tid >> 5;
    float acc[8][4] = {};
    const float4* W1v = (const float4*)W1;
    const float4* W2v = (const float4*)W2;
    for (int k = 0; k < D; ++k) {
        float4 w1 = W1v[k * 32 + c];
        float4 w2 = W2v[k * 32 + c];
        #pragma unroll
        for (int t = 0; t < 8; ++t) {
            float av = a_lds[g + 8 * t][k];
            float mv = m_lds[g + 8 * t][k];
            acc[t][0] = fmaf(av, w1.x, fmaf(mv, w2.x, acc[t][0]));
            acc[t][1] = fmaf(av, w1.y, fmaf(mv, w2.y, acc[t][1]));
            acc[t][2] = fmaf(av, w1.z, fmaf(mv, w2.z, acc[t][2]));
            acc[t][3] = fmaf(av, w1.w, fmaf(mv, w2.w, acc[t][3]));
        }
    }
    float4 bb1 = ((const float4*)b1)[c];
    float4 bb2 = ((const float4*)b2)[c];
    const float bx = bb1.x + bb2.x, by = bb1.y + bb2.y;
    const float bz = bb1.z + bb2.z, bw = bb1.w + bb2.w;
    #pragma unroll
    for (int t = 0; t < 8; ++t) {
        int gnode = block0 + g + 8 * t;
        if (gnode >= N) continue;
        float4 o;
        o.x = acc[t][0] + bx; o.y = acc[t][1] + by;
        o.z = acc[t][2] + bz; o.w = acc[t][3] + bw;
        o.x = (o.x >= 0.f) ? o.x : 0.01f * o.x;
        o.y = (o.y >= 0.f) ? o.y : 0.01f * o.y;
        o.z = (o.z >= 0.f) ? o.z : 0.01f * o.z;
        o.w = (o.w >= 0.f) ? o.w : 0.01f * o.w;
        ((float4*)out)[gnode * 32 + c] = o;
    }
}

extern "C" void kernel_launch(void* const* d_in, const int* in_sizes, int n_in,
                              void* d_out, int out_size, void* d_ws, size_t ws_size,
                              hipStream_t stream) {
    const float* feat = (const float*)d_in[0];
    const int*   rows = (const int*)d_in[1];
    const int*   cols = (const int*)d_in[2];
    const float* vals = (const float*)d_in[3];
    const float* W1   = (const float*)d_in[4];
    const float* b1   = (const float*)d_in[5];
    const float* W2   = (const float*)d_in[6];
    const float* b2   = (const float*)d_in[7];

    const int N = in_sizes[0] / D;
    const int E = in_sizes[1];
    float* out = (float*)d_out;

    const int NBK  = (N + 127) >> 7;          // 128-row buckets
    const int Npad = NBK << 7;

    // Common prefix: ambf | featbf | sedge | WT | row_start
    size_t off = 0;
    unsigned char* ambf = (unsigned char*)d_ws;                    off += (size_t)Npad * 512;
    unsigned short* featbf = (unsigned short*)((char*)d_ws + off); off += (size_t)N * D * 2;
    off = (off + 15) & ~(size_t)15;
    uint2* sedge = (uint2*)((char*)d_ws + off);                    off += (size_t)E * 8;
    unsigned short* WT = (unsigned short*)((char*)d_ws + off);     off += 128 * 256 * 2;
    int* row_start = (int*)((char*)d_ws + off);                    off += (size_t)(N + 1) * 4;
    size_t common = off;

    // --- Tier-1a: bucket CSR build (adds bsedge) ---
    off = (common + 15) & ~(size_t)15;
    uint2* bsedge = (uint2*)((char*)d_ws + off);                   off += (size_t)E * 8;
    int* bcnt   = (int*)((char*)d_ws + off);                       off += (size_t)NBK * 4;
    int* bstart = (int*)((char*)d_ws + off);                       off += (size_t)(NBK + 1) * 4;
    int* bcur   = (int*)((char*)d_ws + off);                       off += (size_t)NBK * 4;
    size_t need1a = off;

    if (ws_size >= need1a && NBK <= 1024 && N <= (1 << 17)) {
        hipMemsetAsync(bcnt, 0, (size_t)NBK * sizeof(int), stream);
        fconv_kernel<<<(N * 32 + 255) / 256, 256, 0, stream>>>(
            (const float4*)feat, (ushort4*)featbf, N * 32);
        wconv_kernel<<<128, 256, 0, stream>>>(W1, W2, WT);
        int epb = (E + 255) / 256;
        bucket_hist_kernel<<<256, 256, 0, stream>>>(rows, bcnt, E, NBK, epb);
        bucket_scan_kernel<<<1, 1024, 0, stream>>>(bcnt, bstart, bcur, NBK, E);
        bucket_scatter_kernel<<<(E + 4095) / 4096, 256, 0, stream>>>(
            rows, cols, vals, bcur, bsedge, E, NBK);
        bucket_sort_kernel<<<NBK, 256, 0, stream>>>(
            bsedge, bstart, sedge, row_start, N, E);
        spmm_ab_kernel<<<(N * 16 + 255) / 256, 256, 0, stream>>>(
            (const float4*)feat, (const ushort8_t*)featbf, row_start, sedge,
            ambf, N);
        mfma_gemm2_kernel<<<(N + BM - 1) / BM, 256, 0, stream>>>(
            ambf, WT, b1, b2, out, N);
        return;
    }

    // --- Tier-1b: round-4 path (full CSR sort, random writes) ---
    const int NB = (N + 1023) / 1024;
    off = (common + 15) & ~(size_t)15;
    int* cursor = (int*)((char*)d_ws + off);                       off += (size_t)N * 4;
    int* btot = (int*)((char*)d_ws + off);                         off += (size_t)NB * 4;
    int* boff = (int*)((char*)d_ws + off);                         off += (size_t)NB * 4;
    size_t need1b = off;

    if (ws_size >= need1b && NB <= 1024) {
        hipMemsetAsync(row_start, 0, (size_t)(N + 1) * sizeof(int), stream);
        fconv_kernel<<<(N * 32 + 255) / 256, 256, 0, stream>>>(
            (const float4*)feat, (ushort4*)featbf, N * 32);
        wconv_kernel<<<128, 256, 0, stream>>>(W1, W2, WT);
        hist_kernel<<<(E + 255) / 256, 256, 0, stream>>>(rows, row_start, E);
        scan_pass1<<<NB, 256, 0, stream>>>(row_start, btot, N);
        scan_pass2<<<1, 1024, 0, stream>>>(btot, boff, NB);
        scan_pass3<<<NB, 256, 0, stream>>>(row_start, cursor, boff, N, E);
        scatter_sort_kernel<<<(E + 255) / 256, 256, 0, stream>>>(
            rows, cols, vals, cursor, sedge, E);
        spmm_ab_kernel<<<(N * 16 + 255) / 256, 256, 0, stream>>>(
            (const float4*)feat, (const ushort8_t*)featbf, row_start, sedge,
            ambf, N);
        mfma_gemm2_kernel<<<(N + BM - 1) / BM, 256, 0, stream>>>(
            ambf, WT, b1, b2, out, N);
        return;
    }

    // --- Tier-2: round-3 fp32 CSR path ---
    off = 0;
    float* h = (float*)d_ws;                           off += (size_t)N * D * 4;
    int* row_start2 = (int*)((char*)d_ws + off);       off += (size_t)(N + 1) * 4;
    int* cursor2    = (int*)((char*)d_ws + off);       off += (size_t)N * 4;
    off = (off + 15) & ~(size_t)15;
    uint2* sedge2   = (uint2*)((char*)d_ws + off);     off += (size_t)E * 8;
    off = (off + 15) & ~(size_t)15;
    unsigned short* WT2 = (unsigned short*)((char*)d_ws + off); off += 128 * 256 * 2;
    int* btot2 = (int*)((char*)d_ws + off);            off += (size_t)NB * 4;
    int* boff2 = (int*)((char*)d_ws + off);            off += (size_t)NB * 4;
    size_t need2 = off;

    if (ws_size >= need2 && NB <= 1024) {
        hipMemsetAsync(row_start2, 0, (size_t)(N + 1) * sizeof(int), stream);
        wconv_kernel<<<128, 256, 0, stream>>>(W1, W2, WT2);
        hist_kernel<<<(E + 255) / 256, 256, 0, stream>>>(rows, row_start2, E);
        scan_pass1<<<NB, 256, 0, stream>>>(row_start2, btot2, N);
        scan_pass2<<<1, 1024, 0, stream>>>(btot2, boff2, NB);
        scan_pass3<<<NB, 256, 0, stream>>>(row_start2, cursor2, boff2, N, E);
        scatter_sort_kernel<<<(E + 255) / 256, 256, 0, stream>>>(
            rows, cols, vals, cursor2, sedge2, E);
        spmm_kernel<<<(N * 64 + 255) / 256, 256, 0, stream>>>(
            (const float2*)feat, row_start2, sedge2, (float2*)h, N);
        mfma_gemm_kernel<<<(N + BM - 1) / BM, 256, 0, stream>>>(
            (const float4*)feat, (const float4*)h, WT2, b1, b2, out, N);
        return;
    }

    // --- Tier-3: atomic scatter + VALU GEMM ---
    size_t hbytes = (size_t)N * D * sizeof(float);
    float* hh = (ws_size >= hbytes) ? (float*)d_ws : out;
    hipMemsetAsync(hh, 0, hbytes, stream);
    edge_scatter_kernel<<<((size_t)E * 32 + 255) / 256, 256, 0, stream>>>(
        (const float4*)feat, rows, cols, vals, hh, E);
    fused_gemm_kernel<<<(N + BM - 1) / BM, 256, 0, stream>>>(
        feat, hh, W1, b1, W2, b2, out, N);
}

// Round 7
// 191.833 us; speedup vs baseline: 7.5119x; 1.0448x over previous
//
#include <hip/hip_runtime.h>

#define D 128
#define BM 64

typedef short short8 __attribute__((ext_vector_type(8)));
typedef unsigned short ushort8_t __attribute__((ext_vector_type(8)));
typedef float f32x4 __attribute__((ext_vector_type(4)));

__device__ __forceinline__ unsigned short f2bf(float x) {
    unsigned u = __float_as_uint(x);
    unsigned r = (u + 0x7fffu + ((u >> 16) & 1u)) >> 16;   // RNE
    return (unsigned short)r;
}
__device__ __forceinline__ float bf2f(unsigned short u) {
    return __uint_as_float(((unsigned)u) << 16);
}

// ===========================================================================
// features fp32 -> bf16 (linear layout)
// ===========================================================================
__global__ __launch_bounds__(256) void fconv_kernel(
    const float4* __restrict__ feat4, ushort4* __restrict__ fbf4, int total)
{
    int i = blockIdx.x * 256 + threadIdx.x;
    if (i < total) {
        float4 v = feat4[i];
        fbf4[i] = make_ushort4(f2bf(v.x), f2bf(v.y), f2bf(v.z), f2bf(v.w));
    }
}

// ===========================================================================
// W -> WT bf16: WT[c][k] = (k<128 ? W1[k][c] : W2[k-128][c]), [128][256]
// ===========================================================================
__global__ __launch_bounds__(256) void wconv_kernel(
    const float* __restrict__ W1, const float* __restrict__ W2,
    unsigned short* __restrict__ WT)
{
    int idx = blockIdx.x * 256 + threadIdx.x;   // 32768
    int c = idx & 127;
    int k = idx >> 7;
    float w = (k < 128) ? W1[k * 128 + c] : W2[(k - 128) * 128 + c];
    WT[c * 256 + k] = f2bf(w);
}

// ===========================================================================
// Bucket CSR build: hist -> scan -> grouped scatter -> per-bucket local sort.
// Buckets are 128 rows; edge key = (r&127)<<17 | col (needs N <= 2^17).
// ===========================================================================

__global__ __launch_bounds__(256) void bucket_hist_kernel(
    const int* __restrict__ rows, int* __restrict__ bcnt, int E, int nb, int epb)
{
    __shared__ int cnt[1024];
    int t = threadIdx.x;
    for (int i = t; i < nb; i += 256) cnt[i] = 0;
    __syncthreads();
    int e0 = blockIdx.x * epb;
    int e1 = e0 + epb; if (e1 > E) e1 = E;
    for (int e = e0 + t; e < e1; e += 256) atomicAdd(&cnt[rows[e] >> 7], 1);
    __syncthreads();
    for (int i = t; i < nb; i += 256)
        if (cnt[i]) atomicAdd(&bcnt[i], cnt[i]);
}

__global__ __launch_bounds__(1024) void bucket_scan_kernel(
    const int* __restrict__ bcnt, int* __restrict__ bstart,
    int* __restrict__ bcur, int nb, int E)
{
    __shared__ int wsum[16];
    int tid = threadIdx.x, lane = tid & 63, wid = tid >> 6;
    int x = (tid < nb) ? bcnt[tid] : 0;
    int v = x;
    #pragma unroll
    for (int off = 1; off < 64; off <<= 1) {
        int y = __shfl_up(v, off, 64);
        if (lane >= off) v += y;
    }
    if (lane == 63) wsum[wid] = v;
    __syncthreads();
    if (wid == 0 && lane < 16) {
        int s = wsum[lane];
        #pragma unroll
        for (int off = 1; off < 16; off <<= 1) {
            int y = __shfl_up(s, off, 64);
            if (lane >= off) s += y;
        }
        wsum[lane] = s;
    }
    __syncthreads();
    int wexcl = wid ? wsum[wid - 1] : 0;
    int excl = wexcl + v - x;
    if (tid < nb) { bstart[tid] = excl; bcur[tid] = excl; }
    if (tid == 0) bstart[nb] = E;
}

__global__ __launch_bounds__(256) void bucket_scatter_kernel(
    const int* __restrict__ rows, const int* __restrict__ cols,
    const float* __restrict__ vals, int* __restrict__ bcur,
    uint2* __restrict__ bsedge, int E, int nb)
{
    __shared__ int cnt[1024];
    __shared__ int base[1024];
    int t = threadIdx.x;
    int e0 = blockIdx.x * 4096;
    for (int i = t; i < nb; i += 256) cnt[i] = 0;
    __syncthreads();
    #pragma unroll
    for (int q = 0; q < 16; ++q) {
        int e = e0 + t + q * 256;
        if (e < E) atomicAdd(&cnt[rows[e] >> 7], 1);
    }
    __syncthreads();
    for (int i = t; i < nb; i += 256) {
        int c = cnt[i];
        if (c) { base[i] = atomicAdd(&bcur[i], c); cnt[i] = 0; }
    }
    __syncthreads();
    #pragma unroll
    for (int q = 0; q < 16; ++q) {
        int e = e0 + t + q * 256;
        if (e < E) {
            int r = rows[e];
            int b = r >> 7;
            int pos = base[b] + atomicAdd(&cnt[b], 1);
            bsedge[pos] = make_uint2(((unsigned)(r & 127) << 17) | (unsigned)cols[e],
                                     __float_as_uint(vals[e]));
        }
    }
}

// One block per bucket: LDS hist(128) + 1-wave pair scan + LDS-cursor scatter.
// Also emits global CSR row_start.
__global__ __launch_bounds__(256) void bucket_sort_kernel(
    const uint2* __restrict__ bsedge,
    const int* __restrict__ bstart,
    uint2* __restrict__ sedge,
    int* __restrict__ row_start,
    int N, int E)
{
    __shared__ int cnt[128];
    __shared__ int base[128];
    const int b = blockIdx.x;
    const int t = threadIdx.x;
    const int s = bstart[b], e = bstart[b + 1];
    if (t < 128) cnt[t] = 0;
    __syncthreads();
    for (int j = s + t; j < e; j += 256)
        atomicAdd(&cnt[bsedge[j].x >> 17], 1);
    __syncthreads();
    if (t < 64) {
        int c0 = cnt[2 * t], c1 = cnt[2 * t + 1];
        int pair = c0 + c1;
        int v = pair;
        #pragma unroll
        for (int off = 1; off < 64; off <<= 1) {
            int y = __shfl_up(v, off, 64);
            if (t >= off) v += y;
        }
        int excl = v - pair;
        base[2 * t]     = excl;
        base[2 * t + 1] = excl + c0;
        cnt[2 * t] = 0;
        cnt[2 * t + 1] = 0;
    }
    __syncthreads();
    const int r0 = b << 7;
    if (t < 128 && r0 + t < N) row_start[r0 + t] = s + base[t];
    if (b == 0 && t == 0) row_start[N] = E;
    for (int j = s + t; j < e; j += 256) {
        uint2 ed = bsedge[j];
        int rl = ed.x >> 17;
        int p = atomicAdd(&cnt[rl], 1);
        sedge[s + base[rl] + p] = make_uint2(ed.x & 0x1FFFFu, ed.y);
    }
}

// ===========================================================================
// FUSED SpMM + MFMA GEMM: block = 256 thr = 64 rows.
// Phase 1: 4 passes of (16 rows x 16 lanes): per-row bf16 gather (4-edge
//   unroll for MLP), a=(f+h), m=(f*h) -> bf16 into swizzled LDS tile.
// Phase 2: round-4-proven MFMA GEMM (waves 2x2, 2x4 frags 16x16x32, K=256).
// ===========================================================================
__global__ __launch_bounds__(256) void spmm_gemm_kernel(
    const float4* __restrict__ feat4,
    const ushort8_t* __restrict__ fbf8,
    const int* __restrict__ row_start,
    const uint2* __restrict__ sedge,
    const unsigned short* __restrict__ WT,
    const float* __restrict__ b1, const float* __restrict__ b2,
    float* __restrict__ out, int N)
{
    __shared__ __align__(16) unsigned char am_raw[64 * 512];   // 32KB

    const int tid = threadIdx.x;
    const int block0 = blockIdx.x * BM;
    const int rq = tid >> 4;      // 0..15 row slot
    const int l  = tid & 15;      // 16 lanes x 8 bf16 = 128 cols

    for (int it = 0; it < 4; ++it) {
        int node = it * 16 + rq;
        int row = block0 + node;
        float acc[8] = {};
        float f[8] = {};
        if (row < N) {
            int s = row_start[row];
            int e = row_start[row + 1];
            int j = s;
            for (; j + 3 < e; j += 4) {
                uint2 e0 = sedge[j],     e1 = sedge[j + 1];
                uint2 e2 = sedge[j + 2], e3 = sedge[j + 3];
                ushort8_t f0 = fbf8[(size_t)e0.x * 16 + l];
                ushort8_t f1 = fbf8[(size_t)e1.x * 16 + l];
                ushort8_t f2 = fbf8[(size_t)e2.x * 16 + l];
                ushort8_t f3 = fbf8[(size_t)e3.x * 16 + l];
                float v0 = __uint_as_float(e0.y), v1 = __uint_as_float(e1.y);
                float v2 = __uint_as_float(e2.y), v3 = __uint_as_float(e3.y);
                #pragma unroll
                for (int q = 0; q < 8; ++q) {
                    acc[q] = fmaf(v0, bf2f(f0[q]), acc[q]);
                    acc[q] = fmaf(v1, bf2f(f1[q]), acc[q]);
                    acc[q] = fmaf(v2, bf2f(f2[q]), acc[q]);
                    acc[q] = fmaf(v3, bf2f(f3[q]), acc[q]);
                }
            }
            for (; j < e; ++j) {
                uint2 e0 = sedge[j];
                float v = __uint_as_float(e0.y);
                ushort8_t f0 = fbf8[(size_t)e0.x * 16 + l];
                #pragma unroll
                for (int q = 0; q < 8; ++q) acc[q] = fmaf(v, bf2f(f0[q]), acc[q]);
            }
            float4 fa = feat4[(size_t)row * 32 + 2 * l];
            float4 fb = feat4[(size_t)row * 32 + 2 * l + 1];
            f[0] = fa.x; f[1] = fa.y; f[2] = fa.z; f[3] = fa.w;
            f[4] = fb.x; f[5] = fb.y; f[6] = fb.z; f[7] = fb.w;
        }
        ushort8_t av, mv;
        #pragma unroll
        for (int q = 0; q < 8; ++q) {
            av[q] = f2bf(f[q] + acc[q]);
            mv[q] = f2bf(f[q] * acc[q]);
        }
        int swz = (node & 7) << 4;
        unsigned char* rowp = am_raw + node * 512;
        *(ushort8_t*)(rowp + ((16 * l) ^ swz))       = av;
        *(ushort8_t*)(rowp + 256 + ((16 * l) ^ swz)) = mv;
    }
    __syncthreads();

    // --- GEMM phase ---
    const int lane = tid & 63;
    const int w    = tid >> 6;
    const int wr   = w >> 1;
    const int wc   = w & 1;
    const int l15  = lane & 15;
    const int lk   = lane >> 4;
    const int rswz = (l15 & 7) << 4;

    f32x4 gacc[2][4] = {};

    const char* WTc = (const char*)WT;
    const unsigned char* arow0 = am_raw + (wr * 32 + l15) * 512;
    const unsigned char* arow1 = arow0 + 16 * 512;

    #pragma unroll
    for (int ks = 0; ks < 8; ++ks) {
        int kbyte = ks * 64 + lk * 16;
        int akoff = kbyte ^ rswz;
        short8 a0 = *(const short8*)(arow0 + akoff);
        short8 a1 = *(const short8*)(arow1 + akoff);
        short8 bfr[4];
        #pragma unroll
        for (int nc = 0; nc < 4; ++nc) {
            int col = wc * 64 + nc * 16 + l15;
            bfr[nc] = *(const short8*)(WTc + col * 512 + kbyte);
        }
        #pragma unroll
        for (int nc = 0; nc < 4; ++nc) {
            gacc[0][nc] = __builtin_amdgcn_mfma_f32_16x16x32_bf16(a0, bfr[nc], gacc[0][nc], 0, 0, 0);
            gacc[1][nc] = __builtin_amdgcn_mfma_f32_16x16x32_bf16(a1, bfr[nc], gacc[1][nc], 0, 0, 0);
        }
    }

    #pragma unroll
    for (int nc = 0; nc < 4; ++nc) {
        int col = wc * 64 + nc * 16 + l15;
        float bias = b1[col] + b2[col];
        #pragma unroll
        for (int mr = 0; mr < 2; ++mr) {
            int rbase = block0 + wr * 32 + mr * 16 + lk * 4;
            #pragma unroll
            for (int r = 0; r < 4; ++r) {
                int row = rbase + r;
                if (row < N) {
                    float v = gacc[mr][nc][r] + bias;
                    out[row * 128 + col] = (v >= 0.f) ? v : 0.01f * v;
                }
            }
        }
    }
}

// ===========================================================================
// Tier-1b kernels: unfused spmm_ab + mfma_gemm2 (round-6 proven)
// ===========================================================================
__global__ __launch_bounds__(256) void spmm_ab_kernel(
    const float4* __restrict__ feat4,
    const ushort8_t* __restrict__ fbf8,
    const int* __restrict__ row_start,
    const uint2* __restrict__ sedge,
    unsigned char* __restrict__ ambf, int N)
{
    int t = blockIdx.x * 256 + threadIdx.x;
    int row = t >> 4;
    int l   = t & 15;
    if (row >= N) return;

    int s = row_start[row];
    int e = row_start[row + 1];

    float acc[8] = {};
    int j = s;
    for (; j + 1 < e; j += 2) {
        uint2 e0 = sedge[j], e1 = sedge[j + 1];
        float v0 = __uint_as_float(e0.y), v1 = __uint_as_float(e1.y);
        ushort8_t f0 = fbf8[(size_t)e0.x * 16 + l];
        ushort8_t f1 = fbf8[(size_t)e1.x * 16 + l];
        #pragma unroll
        for (int q = 0; q < 8; ++q) {
            acc[q] = fmaf(v0, bf2f(f0[q]), acc[q]);
            acc[q] = fmaf(v1, bf2f(f1[q]), acc[q]);
        }
    }
    if (j < e) {
        uint2 e0 = sedge[j];
        float v = __uint_as_float(e0.y);
        ushort8_t f = fbf8[(size_t)e0.x * 16 + l];
        #pragma unroll
        for (int q = 0; q < 8; ++q) acc[q] = fmaf(v, bf2f(f[q]), acc[q]);
    }

    float4 fa = feat4[(size_t)row * 32 + 2 * l];
    float4 fb = feat4[(size_t)row * 32 + 2 * l + 1];
    float f[8] = { fa.x, fa.y, fa.z, fa.w, fb.x, fb.y, fb.z, fb.w };

    ushort8_t av, mv;
    #pragma unroll
    for (int q = 0; q < 8; ++q) {
        av[q] = f2bf(f[q] + acc[q]);
        mv[q] = f2bf(f[q] * acc[q]);
    }

    int swz = (row & 7) << 4;
    unsigned char* rowp = ambf + (size_t)row * 512;
    *(ushort8_t*)(rowp + ((16 * l) ^ swz))       = av;
    *(ushort8_t*)(rowp + 256 + ((16 * l) ^ swz)) = mv;
}

__global__ __launch_bounds__(256) void mfma_gemm2_kernel(
    const unsigned char* __restrict__ ambf,
    const unsigned short* __restrict__ WT,
    const float* __restrict__ b1, const float* __restrict__ b2,
    float* __restrict__ out, int N)
{
    __shared__ __align__(16) unsigned char am_raw[64 * 512];

    const int tid = threadIdx.x;
    const int block0 = blockIdx.x * BM;

    const short8* src = (const short8*)(ambf + (size_t)block0 * 512);
    short8* dst = (short8*)am_raw;
    #pragma unroll
    for (int it = 0; it < 8; ++it) {
        int idx = tid + it * 256;
        dst[idx] = src[idx];
    }
    __syncthreads();

    const int lane = tid & 63;
    const int w    = tid >> 6;
    const int wr   = w >> 1;
    const int wc   = w & 1;
    const int l15  = lane & 15;
    const int lk   = lane >> 4;
    const int rswz = (l15 & 7) << 4;

    f32x4 acc[2][4] = {};

    const char* WTc = (const char*)WT;
    const unsigned char* arow0 = am_raw + (wr * 32 + l15) * 512;
    const unsigned char* arow1 = arow0 + 16 * 512;

    #pragma unroll
    for (int ks = 0; ks < 8; ++ks) {
        int kbyte = ks * 64 + lk * 16;
        int akoff = kbyte ^ rswz;
        short8 a0 = *(const short8*)(arow0 + akoff);
        short8 a1 = *(const short8*)(arow1 + akoff);
        short8 bfr[4];
        #pragma unroll
        for (int nc = 0; nc < 4; ++nc) {
            int col = wc * 64 + nc * 16 + l15;
            bfr[nc] = *(const short8*)(WTc + col * 512 + kbyte);
        }
        #pragma unroll
        for (int nc = 0; nc < 4; ++nc) {
            acc[0][nc] = __builtin_amdgcn_mfma_f32_16x16x32_bf16(a0, bfr[nc], acc[0][nc], 0, 0, 0);
            acc[1][nc] = __builtin_amdgcn_mfma_f32_16x16x32_bf16(a1, bfr[nc], acc[1][nc], 0, 0, 0);
        }
    }

    #pragma unroll
    for (int nc = 0; nc < 4; ++nc) {
        int col = wc * 64 + nc * 16 + l15;
        float bias = b1[col] + b2[col];
        #pragma unroll
        for (int mr = 0; mr < 2; ++mr) {
            int rbase = block0 + wr * 32 + mr * 16 + lk * 4;
            #pragma unroll
            for (int r = 0; r < 4; ++r) {
                int row = rbase + r;
                if (row < N) {
                    float v = acc[mr][nc][r] + bias;
                    out[row * 128 + col] = (v >= 0.f) ? v : 0.01f * v;
                }
            }
        }
    }
}

// ===========================================================================
// Tier-1b/2 CSR kernels (round-3/4, proven)
// ===========================================================================
__global__ __launch_bounds__(256) void hist_kernel(
    const int* __restrict__ rows, int* __restrict__ counts, int E)
{
    int e = blockIdx.x * 256 + threadIdx.x;
    if (e < E) atomicAdd(&counts[rows[e]], 1);
}

__global__ __launch_bounds__(256) void scan_pass1(
    const int* __restrict__ counts, int* __restrict__ btot, int N)
{
    int tid = threadIdx.x;
    int i = blockIdx.x * 1024 + tid * 4;
    int s = 0;
    if (i + 3 < N) {
        int4 v = *(const int4*)(counts + i);
        s = v.x + v.y + v.z + v.w;
    } else {
        for (int q = 0; q < 4; ++q) if (i + q < N) s += counts[i + q];
    }
    #pragma unroll
    for (int off = 32; off >= 1; off >>= 1) s += __shfl_down(s, off, 64);
    __shared__ int ws[4];
    if ((tid & 63) == 0) ws[tid >> 6] = s;
    __syncthreads();
    if (tid == 0) btot[blockIdx.x] = ws[0] + ws[1] + ws[2] + ws[3];
}

__global__ __launch_bounds__(1024) void scan_pass2(
    const int* __restrict__ btot, int* __restrict__ boff, int nb)
{
    __shared__ int wsum[16];
    int tid = threadIdx.x, lane = tid & 63, wid = tid >> 6;
    int x = (tid < nb) ? btot[tid] : 0;
    int v = x;
    #pragma unroll
    for (int off = 1; off < 64; off <<= 1) {
        int y = __shfl_up(v, off, 64);
        if (lane >= off) v += y;
    }
    if (lane == 63) wsum[wid] = v;
    __syncthreads();
    if (wid == 0 && lane < 16) {
        int s = wsum[lane];
        #pragma unroll
        for (int off = 1; off < 16; off <<= 1) {
            int y = __shfl_up(s, off, 64);
            if (lane >= off) s += y;
        }
        wsum[lane] = s;
    }
    __syncthreads();
    int wexcl = wid ? wsum[wid - 1] : 0;
    if (tid < nb) boff[tid] = wexcl + v - x;
}

__global__ __launch_bounds__(256) void scan_pass3(
    int* __restrict__ row_start, int* __restrict__ cursor,
    const int* __restrict__ boff, int N, int E)
{
    int tid = threadIdx.x;
    int base = blockIdx.x * 1024 + tid * 4;
    int c0 = 0, c1 = 0, c2 = 0, c3 = 0;
    if (base + 3 < N) {
        int4 v = *(const int4*)(row_start + base);
        c0 = v.x; c1 = v.y; c2 = v.z; c3 = v.w;
    } else {
        if (base + 0 < N) c0 = row_start[base + 0];
        if (base + 1 < N) c1 = row_start[base + 1];
        if (base + 2 < N) c2 = row_start[base + 2];
        if (base + 3 < N) c3 = row_start[base + 3];
    }
    int s0 = c0, s1 = s0 + c1, s2 = s1 + c2, s3 = s2 + c3;
    int lane = tid & 63, wid = tid >> 6;
    int v = s3;
    #pragma unroll
    for (int off = 1; off < 64; off <<= 1) {
        int y = __shfl_up(v, off, 64);
        if (lane >= off) v += y;
    }
    __shared__ int ws[4];
    if (lane == 63) ws[wid] = v;
    __syncthreads();
    int wexcl = 0;
    for (int q = 0; q < wid; ++q) wexcl += ws[q];
    int texcl = wexcl + (v - s3) + boff[blockIdx.x];
    int e0 = texcl, e1 = texcl + s0, e2 = texcl + s1, e3 = texcl + s2;
    if (base + 0 < N) { row_start[base + 0] = e0; cursor[base + 0] = e0; }
    if (base + 1 < N) { row_start[base + 1] = e1; cursor[base + 1] = e1; }
    if (base + 2 < N) { row_start[base + 2] = e2; cursor[base + 2] = e2; }
    if (base + 3 < N) { row_start[base + 3] = e3; cursor[base + 3] = e3; }
    if (blockIdx.x == 0 && tid == 0) row_start[N] = E;
}

__global__ __launch_bounds__(256) void scatter_sort_kernel(
    const int* __restrict__ rows, const int* __restrict__ cols,
    const float* __restrict__ vals, int* __restrict__ cursor,
    uint2* __restrict__ sedge, int E)
{
    int e = blockIdx.x * 256 + threadIdx.x;
    if (e < E) {
        int r = rows[e];
        int p = atomicAdd(&cursor[r], 1);
        sedge[p] = make_uint2((unsigned)cols[e], __float_as_uint(vals[e]));
    }
}

__global__ __launch_bounds__(256) void spmm_kernel(
    const float2* __restrict__ feat2,
    const int* __restrict__ row_start,
    const uint2* __restrict__ sedge,
    float2* __restrict__ h2, int N)
{
    int gw = (blockIdx.x * 256 + threadIdx.x) >> 6;
    int lane = threadIdx.x & 63;
    if (gw >= N) return;
    int s = row_start[gw];
    int e = row_start[gw + 1];
    float2 acc = make_float2(0.f, 0.f);
    int j = s;
    for (; j + 1 < e; j += 2) {
        uint2 e0 = sedge[j], e1 = sedge[j + 1];
        float v0 = __uint_as_float(e0.y), v1 = __uint_as_float(e1.y);
        float2 f0 = feat2[(size_t)e0.x * 64 + lane];
        float2 f1 = feat2[(size_t)e1.x * 64 + lane];
        acc.x = fmaf(v0, f0.x, acc.x);
        acc.y = fmaf(v0, f0.y, acc.y);
        acc.x = fmaf(v1, f1.x, acc.x);
        acc.y = fmaf(v1, f1.y, acc.y);
    }
    if (j < e) {
        uint2 e0 = sedge[j];
        float v = __uint_as_float(e0.y);
        float2 f = feat2[(size_t)e0.x * 64 + lane];
        acc.x = fmaf(v, f.x, acc.x);
        acc.y = fmaf(v, f.y, acc.y);
    }
    h2[(size_t)gw * 64 + lane] = acc;
}

__global__ __launch_bounds__(256) void mfma_gemm_kernel(
    const float4* __restrict__ feat4, const float4* __restrict__ h4,
    const unsigned short* __restrict__ WT,
    const float* __restrict__ b1, const float* __restrict__ b2,
    float* __restrict__ out, int N)
{
    __shared__ __align__(16) unsigned char am_raw[64 * 512];
    const int tid = threadIdx.x;
    const int block0 = blockIdx.x * BM;
    #pragma unroll
    for (int it = 0; it < 8; ++it) {
        int idx  = tid + it * 256;
        int node = idx >> 5;
        int p    = idx & 31;
        int g    = block0 + node;
        float4 fv = make_float4(0.f, 0.f, 0.f, 0.f);
        float4 hv = make_float4(0.f, 0.f, 0.f, 0.f);
        if (g < N) { fv = feat4[g * 32 + p]; hv = h4[g * 32 + p]; }
        ushort4 av = make_ushort4(f2bf(fv.x + hv.x), f2bf(fv.y + hv.y),
                                  f2bf(fv.z + hv.z), f2bf(fv.w + hv.w));
        ushort4 mv = make_ushort4(f2bf(fv.x * hv.x), f2bf(fv.y * hv.y),
                                  f2bf(fv.z * hv.z), f2bf(fv.w * hv.w));
        int swz = (node & 7) << 4;
        *(ushort4*)(am_raw + node * 512 + ((p * 8) ^ swz))       = av;
        *(ushort4*)(am_raw + node * 512 + ((256 + p * 8) ^ swz)) = mv;
    }
    __syncthreads();
    const int lane = tid & 63;
    const int w    = tid >> 6;
    const int wr   = w >> 1;
    const int wc   = w & 1;
    const int l15  = lane & 15;
    const int lk   = lane >> 4;
    const int rswz = (l15 & 7) << 4;
    f32x4 acc[2][4] = {};
    const char* WTc = (const char*)WT;
    const unsigned char* arow0 = am_raw + (wr * 32 + l15) * 512;
    const unsigned char* arow1 = arow0 + 16 * 512;
    #pragma unroll
    for (int ks = 0; ks < 8; ++ks) {
        int kbyte = ks * 64 + lk * 16;
        int akoff = kbyte ^ rswz;
        short8 a0 = *(const short8*)(arow0 + akoff);
        short8 a1 = *(const short8*)(arow1 + akoff);
        short8 bfr[4];
        #pragma unroll
        for (int nc = 0; nc < 4; ++nc) {
            int col = wc * 64 + nc * 16 + l15;
            bfr[nc] = *(const short8*)(WTc + col * 512 + kbyte);
        }
        #pragma unroll
        for (int nc = 0; nc < 4; ++nc) {
            acc[0][nc] = __builtin_amdgcn_mfma_f32_16x16x32_bf16(a0, bfr[nc], acc[0][nc], 0, 0, 0);
            acc[1][nc] = __builtin_amdgcn_mfma_f32_16x16x32_bf16(a1, bfr[nc], acc[1][nc], 0, 0, 0);
        }
    }
    #pragma unroll
    for (int nc = 0; nc < 4; ++nc) {
        int col = wc * 64 + nc * 16 + l15;
        float bias = b1[col] + b2[col];
        #pragma unroll
        for (int mr = 0; mr < 2; ++mr) {
            int rbase = block0 + wr * 32 + mr * 16 + lk * 4;
            #pragma unroll
            for (int r = 0; r < 4; ++r) {
                int row = rbase + r;
                if (row < N) {
                    float v = acc[mr][nc][r] + bias;
                    out[row * 128 + col] = (v >= 0.f) ? v : 0.01f * v;
                }
            }
        }
    }
}

// ===========================================================================
// Tier-3: atomic scatter + fp32 VALU GEMM
// ===========================================================================
__global__ __launch_bounds__(256) void edge_scatter_kernel(
    const float4* __restrict__ feat4, const int* __restrict__ rows,
    const int* __restrict__ cols, const float* __restrict__ vals,
    float* __restrict__ h, int E)
{
    int idx = blockIdx.x * 256 + threadIdx.x;
    if (idx >= E * 32) return;
    int e = idx >> 5;
    int p = idx & 31;
    int r = rows[e];
    int c = cols[e];
    float v = vals[e];
    float4 f = feat4[c * 32 + p];
    float* hr = h + (long long)r * D + p * 4;
    unsafeAtomicAdd(hr + 0, v * f.x);
    unsafeAtomicAdd(hr + 1, v * f.y);
    unsafeAtomicAdd(hr + 2, v * f.z);
    unsafeAtomicAdd(hr + 3, v * f.w);
}

__global__ __launch_bounds__(256) void fused_gemm_kernel(
    const float* __restrict__ feat, const float* __restrict__ h,
    const float* __restrict__ W1, const float* __restrict__ b1,
    const float* __restrict__ W2, const float* __restrict__ b2,
    float* __restrict__ out, int N)
{
    __shared__ float a_lds[BM][D];
    __shared__ float m_lds[BM][D];
    const int tid = threadIdx.x;
    const int block0 = blockIdx.x * BM;
    const float4* feat4 = (const float4*)feat;
    const float4* h4    = (const float4*)h;
    #pragma unroll
    for (int it = 0; it < 8; ++it) {
        int idx  = tid + it * 256;
        int node = idx >> 5;
        int p    = idx & 31;
        int gnode = block0 + node;
        float4 fv = make_float4(0.f, 0.f, 0.f, 0.f);
        float4 hv = make_float4(0.f, 0.f, 0.f, 0.f);
        if (gnode < N) { fv = feat4[gnode * 32 + p]; hv = h4[gnode * 32 + p]; }
        float4 av = make_float4(fv.x + hv.x, fv.y + hv.y, fv.z + hv.z, fv.w + hv.w);
        float4 mv = make_float4(fv.x * hv.x, fv.y * hv.y, fv.z * hv.z, fv.w * hv.w);
        *(float4*)&a_lds[node][p * 4] = av;
        *(float4*)&m_lds[node][p * 4] = mv;
    }
    __syncthreads();
    const int c = tid & 31;
    const int g = tid >> 5;
    float acc[8][4] = {};
    const float4* W1v = (const float4*)W1;
    const float4* W2v = (const float4*)W2;
    for (int k = 0; k < D; ++k) {
        float4 w1 = W1v[k * 32 + c];
        float4 w2 = W2v[k * 32 + c];
        #pragma unroll
        for (int t = 0; t < 8; ++t) {
            float av = a_lds[g + 8 * t][k];
            float mv = m_lds[g + 8 * t][k];
            acc[t][0] = fmaf(av, w1.x, fmaf(mv, w2.x, acc[t][0]));
            acc[t][1] = fmaf(av, w1.y, fmaf(mv, w2.y, acc[t][1]));
            acc[t][2] = fmaf(av, w1.z, fmaf(mv, w2.z, acc[t][2]));
            acc[t][3] = fmaf(av, w1.w, fmaf(mv, w2.w, acc[t][3]));
        }
    }
    float4 bb1 = ((const float4*)b1)[c];
    float4 bb2 = ((const float4*)b2)[c];
    const float bx = bb1.x + bb2.x, by = bb1.y + bb2.y;
    const float bz = bb1.z + bb2.z, bw = bb1.w + bb2.w;
    #pragma unroll
    for (int t = 0; t < 8; ++t) {
        int gnode = block0 + g + 8 * t;
        if (gnode >= N) continue;
        float4 o;
        o.x = acc[t][0] + bx; o.y = acc[t][1] + by;
        o.z = acc[t][2] + bz; o.w = acc[t][3] + bw;
        o.x = (o.x >= 0.f) ? o.x : 0.01f * o.x;
        o.y = (o.y >= 0.f) ? o.y : 0.01f * o.y;
        o.z = (o.z >= 0.f) ? o.z : 0.01f * o.z;
        o.w = (o.w >= 0.f) ? o.w : 0.01f * o.w;
        ((float4*)out)[gnode * 32 + c] = o;
    }
}

extern "C" void kernel_launch(void* const* d_in, const int* in_sizes, int n_in,
                              void* d_out, int out_size, void* d_ws, size_t ws_size,
                              hipStream_t stream) {
    const float* feat = (const float*)d_in[0];
    const int*   rows = (const int*)d_in[1];
    const int*   cols = (const int*)d_in[2];
    const float* vals = (const float*)d_in[3];
    const float* W1   = (const float*)d_in[4];
    const float* b1   = (const float*)d_in[5];
    const float* W2   = (const float*)d_in[6];
    const float* b2   = (const float*)d_in[7];

    const int N = in_sizes[0] / D;
    const int E = in_sizes[1];
    float* out = (float*)d_out;

    const int NBK  = (N + 127) >> 7;          // 128-row buckets
    const int Npad = NBK << 7;

    // --- Tier-1a (fused): featbf | sedge | WT | row_start | bsedge | bcnt | bstart | bcur
    size_t off = 0;
    unsigned short* featbf = (unsigned short*)d_ws;                off += (size_t)N * D * 2;
    off = (off + 15) & ~(size_t)15;
    uint2* sedge = (uint2*)((char*)d_ws + off);                    off += (size_t)E * 8;
    unsigned short* WT = (unsigned short*)((char*)d_ws + off);     off += 128 * 256 * 2;
    int* row_start = (int*)((char*)d_ws + off);                    off += (size_t)(N + 1) * 4;
    off = (off + 15) & ~(size_t)15;
    uint2* bsedge = (uint2*)((char*)d_ws + off);                   off += (size_t)E * 8;
    int* bcnt   = (int*)((char*)d_ws + off);                       off += (size_t)NBK * 4;
    int* bstart = (int*)((char*)d_ws + off);                       off += (size_t)(NBK + 1) * 4;
    int* bcur   = (int*)((char*)d_ws + off);                       off += (size_t)NBK * 4;
    size_t need1a = off;

    if (ws_size >= need1a && NBK <= 1024 && N <= (1 << 17)) {
        hipMemsetAsync(bcnt, 0, (size_t)NBK * sizeof(int), stream);
        fconv_kernel<<<(N * 32 + 255) / 256, 256, 0, stream>>>(
            (const float4*)feat, (ushort4*)featbf, N * 32);
        wconv_kernel<<<128, 256, 0, stream>>>(W1, W2, WT);
        int epb = (E + 255) / 256;
        bucket_hist_kernel<<<256, 256, 0, stream>>>(rows, bcnt, E, NBK, epb);
        bucket_scan_kernel<<<1, 1024, 0, stream>>>(bcnt, bstart, bcur, NBK, E);
        bucket_scatter_kernel<<<(E + 4095) / 4096, 256, 0, stream>>>(
            rows, cols, vals, bcur, bsedge, E, NBK);
        bucket_sort_kernel<<<NBK, 256, 0, stream>>>(
            bsedge, bstart, sedge, row_start, N, E);
        spmm_gemm_kernel<<<(N + BM - 1) / BM, 256, 0, stream>>>(
            (const float4*)feat, (const ushort8_t*)featbf, row_start, sedge,
            WT, b1, b2, out, N);
        return;
    }

    // --- Tier-1b: unfused round-6 path (adds ambf, full-CSR build) ---
    const int NB = (N + 1023) / 1024;
    off = 0;
    unsigned char* ambf = (unsigned char*)d_ws;                    off += (size_t)Npad * 512;
    featbf = (unsigned short*)((char*)d_ws + off);                 off += (size_t)N * D * 2;
    off = (off + 15) & ~(size_t)15;
    sedge = (uint2*)((char*)d_ws + off);                           off += (size_t)E * 8;
    WT = (unsigned short*)((char*)d_ws + off);                     off += 128 * 256 * 2;
    row_start = (int*)((char*)d_ws + off);                         off += (size_t)(N + 1) * 4;
    off = (off + 15) & ~(size_t)15;
    int* cursor = (int*)((char*)d_ws + off);                       off += (size_t)N * 4;
    int* btot = (int*)((char*)d_ws + off);                         off += (size_t)NB * 4;
    int* boff = (int*)((char*)d_ws + off);                         off += (size_t)NB * 4;
    size_t need1b = off;

    if (ws_size >= need1b && NB <= 1024) {
        hipMemsetAsync(row_start, 0, (size_t)(N + 1) * sizeof(int), stream);
        fconv_kernel<<<(N * 32 + 255) / 256, 256, 0, stream>>>(
            (const float4*)feat, (ushort4*)featbf, N * 32);
        wconv_kernel<<<128, 256, 0, stream>>>(W1, W2, WT);
        hist_kernel<<<(E + 255) / 256, 256, 0, stream>>>(rows, row_start, E);
        scan_pass1<<<NB, 256, 0, stream>>>(row_start, btot, N);
        scan_pass2<<<1, 1024, 0, stream>>>(btot, boff, NB);
        scan_pass3<<<NB, 256, 0, stream>>>(row_start, cursor, boff, N, E);
        scatter_sort_kernel<<<(E + 255) / 256, 256, 0, stream>>>(
            rows, cols, vals, cursor, sedge, E);
        spmm_ab_kernel<<<(N * 16 + 255) / 256, 256, 0, stream>>>(
            (const float4*)feat, (const ushort8_t*)featbf, row_start, sedge,
            ambf, N);
        mfma_gemm2_kernel<<<(N + BM - 1) / BM, 256, 0, stream>>>(
            ambf, WT, b1, b2, out, N);
        return;
    }

    // --- Tier-2: round-3 fp32 CSR path ---
    off = 0;
    float* h = (float*)d_ws;                           off += (size_t)N * D * 4;
    int* row_start2 = (int*)((char*)d_ws + off);       off += (size_t)(N + 1) * 4;
    int* cursor2    = (int*)((char*)d_ws + off);       off += (size_t)N * 4;
    off = (off + 15) & ~(size_t)15;
    uint2* sedge2   = (uint2*)((char*)d_ws + off);     off += (size_t)E * 8;
    off = (off + 15) & ~(size_t)15;
    unsigned short* WT2 = (unsigned short*)((char*)d_ws + off); off += 128 * 256 * 2;
    int* btot2 = (int*)((char*)d_ws + off);            off += (size_t)NB * 4;
    int* boff2 = (int*)((char*)d_ws + off);            off += (size_t)NB * 4;
    size_t need2 = off;

    if (ws_size >= need2 && NB <= 1024) {
        hipMemsetAsync(row_start2, 0, (size_t)(N + 1) * sizeof(int), stream);
        wconv_kernel<<<128, 256, 0, stream>>>(W1, W2, WT2);
        hist_kernel<<<(E + 255) / 256, 256, 0, stream>>>(rows, row_start2, E);
        scan_pass1<<<NB, 256, 0, stream>>>(row_start2, btot2, N);
        scan_pass2<<<1, 1024, 0, stream>>>(btot2, boff2, NB);
        scan_pass3<<<NB, 256, 0, stream>>>(row_start2, cursor2, boff2, N, E);
        scatter_sort_kernel<<<(E + 255) / 256, 256, 0, stream>>>(
            rows, cols, vals, cursor2, sedge2, E);
        spmm_kernel<<<(N * 64 + 255) / 256, 256, 0, stream>>>(
            (const float2*)feat, row_start2, sedge2, (float2*)h, N);
        mfma_gemm_kernel<<<(N + BM - 1) / BM, 256, 0, stream>>>(
            (const float4*)feat, (const float4*)h, WT2, b1, b2, out, N);
        return;
    }

    // --- Tier-3: atomic scatter + VALU GEMM ---
    size_t hbytes = (size_t)N * D * sizeof(float);
    float* hh = (ws_size >= hbytes) ? (float*)d_ws : out;
    hipMemsetAsync(hh, 0, hbytes, stream);
    edge_scatter_kernel<<<((size_t)E * 32 + 255) / 256, 256, 0, stream>>>(
        (const float4*)feat, rows, cols, vals, hh, E);
    fused_gemm_kernel<<<(N + BM - 1) / BM, 256, 0, stream>>>(
        feat, hh, W1, b1, W2, b2, out, N);
}

// Round 8
// 184.619 us; speedup vs baseline: 7.8055x; 1.0391x over previous
//
#include <hip/hip_runtime.h>

#define D 128
#define BM 64

typedef short short8 __attribute__((ext_vector_type(8)));
typedef unsigned short ushort8_t __attribute__((ext_vector_type(8)));
typedef float f32x4 __attribute__((ext_vector_type(4)));

__device__ __forceinline__ unsigned short f2bf(float x) {
    unsigned u = __float_as_uint(x);
    unsigned r = (u + 0x7fffu + ((u >> 16) & 1u)) >> 16;   // RNE
    return (unsigned short)r;
}
__device__ __forceinline__ float bf2f(unsigned short u) {
    return __uint_as_float(((unsigned)u) << 16);
}

// ===========================================================================
// features fp32 -> bf16 (linear layout)
// ===========================================================================
__global__ __launch_bounds__(256) void fconv_kernel(
    const float4* __restrict__ feat4, ushort4* __restrict__ fbf4, int total)
{
    int i = blockIdx.x * 256 + threadIdx.x;
    if (i < total) {
        float4 v = feat4[i];
        fbf4[i] = make_ushort4(f2bf(v.x), f2bf(v.y), f2bf(v.z), f2bf(v.w));
    }
}

// ===========================================================================
// W -> WT bf16: WT[c][k] = (k<128 ? W1[k][c] : W2[k-128][c]), [128][256]
// ===========================================================================
__global__ __launch_bounds__(256) void wconv_kernel(
    const float* __restrict__ W1, const float* __restrict__ W2,
    unsigned short* __restrict__ WT)
{
    int idx = blockIdx.x * 256 + threadIdx.x;   // 32768
    int c = idx & 127;
    int k = idx >> 7;
    float w = (k < 128) ? W1[k * 128 + c] : W2[(k - 128) * 128 + c];
    WT[c * 256 + k] = f2bf(w);
}

// ===========================================================================
// Bucket CSR build: hist -> scan -> grouped scatter -> per-bucket local sort.
// Buckets are 128 rows; edge key = (r&127)<<17 | col (needs N <= 2^17).
// ===========================================================================

__global__ __launch_bounds__(256) void bucket_hist_kernel(
    const int* __restrict__ rows, int* __restrict__ bcnt, int E, int nb, int epb)
{
    __shared__ int cnt[1024];
    int t = threadIdx.x;
    for (int i = t; i < nb; i += 256) cnt[i] = 0;
    __syncthreads();
    int e0 = blockIdx.x * epb;
    int e1 = e0 + epb; if (e1 > E) e1 = E;
    for (int e = e0 + t; e < e1; e += 256) atomicAdd(&cnt[rows[e] >> 7], 1);
    __syncthreads();
    for (int i = t; i < nb; i += 256)
        if (cnt[i]) atomicAdd(&bcnt[i], cnt[i]);
}

__global__ __launch_bounds__(1024) void bucket_scan_kernel(
    const int* __restrict__ bcnt, int* __restrict__ bstart,
    int* __restrict__ bcur, int nb, int E)
{
    __shared__ int wsum[16];
    int tid = threadIdx.x, lane = tid & 63, wid = tid >> 6;
    int x = (tid < nb) ? bcnt[tid] : 0;
    int v = x;
    #pragma unroll
    for (int off = 1; off < 64; off <<= 1) {
        int y = __shfl_up(v, off, 64);
        if (lane >= off) v += y;
    }
    if (lane == 63) wsum[wid] = v;
    __syncthreads();
    if (wid == 0 && lane < 16) {
        int s = wsum[lane];
        #pragma unroll
        for (int off = 1; off < 16; off <<= 1) {
            int y = __shfl_up(s, off, 64);
            if (lane >= off) s += y;
        }
        wsum[lane] = s;
    }
    __syncthreads();
    int wexcl = wid ? wsum[wid - 1] : 0;
    int excl = wexcl + v - x;
    if (tid < nb) { bstart[tid] = excl; bcur[tid] = excl; }
    if (tid == 0) bstart[nb] = E;
}

__global__ __launch_bounds__(256) void bucket_scatter_kernel(
    const int* __restrict__ rows, const int* __restrict__ cols,
    const float* __restrict__ vals, int* __restrict__ bcur,
    uint2* __restrict__ bsedge, int E, int nb)
{
    __shared__ int cnt[1024];
    __shared__ int base[1024];
    int t = threadIdx.x;
    int e0 = blockIdx.x * 4096;
    for (int i = t; i < nb; i += 256) cnt[i] = 0;
    __syncthreads();
    #pragma unroll
    for (int q = 0; q < 16; ++q) {
        int e = e0 + t + q * 256;
        if (e < E) atomicAdd(&cnt[rows[e] >> 7], 1);
    }
    __syncthreads();
    for (int i = t; i < nb; i += 256) {
        int c = cnt[i];
        if (c) { base[i] = atomicAdd(&bcur[i], c); cnt[i] = 0; }
    }
    __syncthreads();
    #pragma unroll
    for (int q = 0; q < 16; ++q) {
        int e = e0 + t + q * 256;
        if (e < E) {
            int r = rows[e];
            int b = r >> 7;
            int pos = base[b] + atomicAdd(&cnt[b], 1);
            bsedge[pos] = make_uint2(((unsigned)(r & 127) << 17) | (unsigned)cols[e],
                                     __float_as_uint(vals[e]));
        }
    }
}

// One block per bucket: LDS hist(128) + 1-wave pair scan + LDS-cursor scatter.
// Also emits global CSR row_start.
__global__ __launch_bounds__(256) void bucket_sort_kernel(
    const uint2* __restrict__ bsedge,
    const int* __restrict__ bstart,
    uint2* __restrict__ sedge,
    int* __restrict__ row_start,
    int N, int E)
{
    __shared__ int cnt[128];
    __shared__ int base[128];
    const int b = blockIdx.x;
    const int t = threadIdx.x;
    const int s = bstart[b], e = bstart[b + 1];
    if (t < 128) cnt[t] = 0;
    __syncthreads();
    for (int j = s + t; j < e; j += 256)
        atomicAdd(&cnt[bsedge[j].x >> 17], 1);
    __syncthreads();
    if (t < 64) {
        int c0 = cnt[2 * t], c1 = cnt[2 * t + 1];
        int pair = c0 + c1;
        int v = pair;
        #pragma unroll
        for (int off = 1; off < 64; off <<= 1) {
            int y = __shfl_up(v, off, 64);
            if (t >= off) v += y;
        }
        int excl = v - pair;
        base[2 * t]     = excl;
        base[2 * t + 1] = excl + c0;
        cnt[2 * t] = 0;
        cnt[2 * t + 1] = 0;
    }
    __syncthreads();
    const int r0 = b << 7;
    if (t < 128 && r0 + t < N) row_start[r0 + t] = s + base[t];
    if (b == 0 && t == 0) row_start[N] = E;
    for (int j = s + t; j < e; j += 256) {
        uint2 ed = bsedge[j];
        int rl = ed.x >> 17;
        int p = atomicAdd(&cnt[rl], 1);
        sedge[s + base[rl] + p] = make_uint2(ed.x & 0x1FFFFu, ed.y);
    }
}

// ===========================================================================
// FUSED SpMM + MFMA GEMM, 16-row blocks (occupancy-first).
// Phase 1: one row per 16-lane group (no serial row loop), 4-edge unroll,
//   a=(f+h), m=(f*h) bf16 -> 8KB swizzled LDS tile.
// Phase 2: 4 waves x 32 cols; per wave 8 k-steps x {1 A ds_read, 2 WT, 2 MFMA}.
// Grid = ceil(N/16) = 6250 blocks -> ~24 blocks/CU.
// ===========================================================================
__global__ __launch_bounds__(256) void spmm_gemm16_kernel(
    const float4* __restrict__ feat4,
    const ushort8_t* __restrict__ fbf8,
    const int* __restrict__ row_start,
    const uint2* __restrict__ sedge,
    const unsigned short* __restrict__ WT,
    const float* __restrict__ b1, const float* __restrict__ b2,
    float* __restrict__ out, int N)
{
    __shared__ __align__(16) unsigned char am_raw[16 * 512];   // 8KB

    const int tid = threadIdx.x;
    const int block0 = blockIdx.x * 16;
    const int rq = tid >> 4;      // 0..15 row slot
    const int l  = tid & 15;      // 16 lanes x 8 bf16 = 128 cols

    int row = block0 + rq;
    float acc[8] = {};
    float f[8] = {};
    if (row < N) {
        int s = row_start[row];
        int e = row_start[row + 1];
        int j = s;
        for (; j + 3 < e; j += 4) {
            uint2 e0 = sedge[j],     e1 = sedge[j + 1];
            uint2 e2 = sedge[j + 2], e3 = sedge[j + 3];
            ushort8_t f0 = fbf8[(size_t)e0.x * 16 + l];
            ushort8_t f1 = fbf8[(size_t)e1.x * 16 + l];
            ushort8_t f2 = fbf8[(size_t)e2.x * 16 + l];
            ushort8_t f3 = fbf8[(size_t)e3.x * 16 + l];
            float v0 = __uint_as_float(e0.y), v1 = __uint_as_float(e1.y);
            float v2 = __uint_as_float(e2.y), v3 = __uint_as_float(e3.y);
            #pragma unroll
            for (int q = 0; q < 8; ++q) {
                acc[q] = fmaf(v0, bf2f(f0[q]), acc[q]);
                acc[q] = fmaf(v1, bf2f(f1[q]), acc[q]);
                acc[q] = fmaf(v2, bf2f(f2[q]), acc[q]);
                acc[q] = fmaf(v3, bf2f(f3[q]), acc[q]);
            }
        }
        for (; j < e; ++j) {
            uint2 e0 = sedge[j];
            float v = __uint_as_float(e0.y);
            ushort8_t f0 = fbf8[(size_t)e0.x * 16 + l];
            #pragma unroll
            for (int q = 0; q < 8; ++q) acc[q] = fmaf(v, bf2f(f0[q]), acc[q]);
        }
        float4 fa = feat4[(size_t)row * 32 + 2 * l];
        float4 fb = feat4[(size_t)row * 32 + 2 * l + 1];
        f[0] = fa.x; f[1] = fa.y; f[2] = fa.z; f[3] = fa.w;
        f[4] = fb.x; f[5] = fb.y; f[6] = fb.z; f[7] = fb.w;
    }
    ushort8_t av, mv;
    #pragma unroll
    for (int q = 0; q < 8; ++q) {
        av[q] = f2bf(f[q] + acc[q]);
        mv[q] = f2bf(f[q] * acc[q]);
    }
    {
        int swz = (rq & 7) << 4;
        unsigned char* rowp = am_raw + rq * 512;
        *(ushort8_t*)(rowp + ((16 * l) ^ swz))       = av;
        *(ushort8_t*)(rowp + 256 + ((16 * l) ^ swz)) = mv;
    }
    __syncthreads();

    // --- GEMM phase: wave w covers cols w*32..w*32+31 ---
    const int lane = tid & 63;
    const int w    = tid >> 6;
    const int l15  = lane & 15;
    const int lk   = lane >> 4;
    const int rswz = (l15 & 7) << 4;

    f32x4 gacc[2] = {};
    const char* WTc = (const char*)WT;
    const unsigned char* arow = am_raw + l15 * 512;

    #pragma unroll
    for (int ks = 0; ks < 8; ++ks) {
        int kbyte = ks * 64 + lk * 16;
        short8 a = *(const short8*)(arow + (kbyte ^ rswz));
        #pragma unroll
        for (int nc = 0; nc < 2; ++nc) {
            int col = w * 32 + nc * 16 + l15;
            short8 b = *(const short8*)(WTc + col * 512 + kbyte);
            gacc[nc] = __builtin_amdgcn_mfma_f32_16x16x32_bf16(a, b, gacc[nc], 0, 0, 0);
        }
    }

    #pragma unroll
    for (int nc = 0; nc < 2; ++nc) {
        int col = w * 32 + nc * 16 + l15;
        float bias = b1[col] + b2[col];
        int rbase = block0 + lk * 4;
        #pragma unroll
        for (int r = 0; r < 4; ++r) {
            int orow = rbase + r;
            if (orow < N) {
                float v = gacc[nc][r] + bias;
                out[orow * 128 + col] = (v >= 0.f) ? v : 0.01f * v;
            }
        }
    }
}

// ===========================================================================
// Tier-1b kernels: unfused spmm_ab + mfma_gemm2 (round-6 proven)
// ===========================================================================
__global__ __launch_bounds__(256) void spmm_ab_kernel(
    const float4* __restrict__ feat4,
    const ushort8_t* __restrict__ fbf8,
    const int* __restrict__ row_start,
    const uint2* __restrict__ sedge,
    unsigned char* __restrict__ ambf, int N)
{
    int t = blockIdx.x * 256 + threadIdx.x;
    int row = t >> 4;
    int l   = t & 15;
    if (row >= N) return;

    int s = row_start[row];
    int e = row_start[row + 1];

    float acc[8] = {};
    int j = s;
    for (; j + 1 < e; j += 2) {
        uint2 e0 = sedge[j], e1 = sedge[j + 1];
        float v0 = __uint_as_float(e0.y), v1 = __uint_as_float(e1.y);
        ushort8_t f0 = fbf8[(size_t)e0.x * 16 + l];
        ushort8_t f1 = fbf8[(size_t)e1.x * 16 + l];
        #pragma unroll
        for (int q = 0; q < 8; ++q) {
            acc[q] = fmaf(v0, bf2f(f0[q]), acc[q]);
            acc[q] = fmaf(v1, bf2f(f1[q]), acc[q]);
        }
    }
    if (j < e) {
        uint2 e0 = sedge[j];
        float v = __uint_as_float(e0.y);
        ushort8_t f = fbf8[(size_t)e0.x * 16 + l];
        #pragma unroll
        for (int q = 0; q < 8; ++q) acc[q] = fmaf(v, bf2f(f[q]), acc[q]);
    }

    float4 fa = feat4[(size_t)row * 32 + 2 * l];
    float4 fb = feat4[(size_t)row * 32 + 2 * l + 1];
    float f[8] = { fa.x, fa.y, fa.z, fa.w, fb.x, fb.y, fb.z, fb.w };

    ushort8_t av, mv;
    #pragma unroll
    for (int q = 0; q < 8; ++q) {
        av[q] = f2bf(f[q] + acc[q]);
        mv[q] = f2bf(f[q] * acc[q]);
    }

    int swz = (row & 7) << 4;
    unsigned char* rowp = ambf + (size_t)row * 512;
    *(ushort8_t*)(rowp + ((16 * l) ^ swz))       = av;
    *(ushort8_t*)(rowp + 256 + ((16 * l) ^ swz)) = mv;
}

__global__ __launch_bounds__(256) void mfma_gemm2_kernel(
    const unsigned char* __restrict__ ambf,
    const unsigned short* __restrict__ WT,
    const float* __restrict__ b1, const float* __restrict__ b2,
    float* __restrict__ out, int N)
{
    __shared__ __align__(16) unsigned char am_raw[64 * 512];

    const int tid = threadIdx.x;
    const int block0 = blockIdx.x * BM;

    const short8* src = (const short8*)(ambf + (size_t)block0 * 512);
    short8* dst = (short8*)am_raw;
    #pragma unroll
    for (int it = 0; it < 8; ++it) {
        int idx = tid + it * 256;
        dst[idx] = src[idx];
    }
    __syncthreads();

    const int lane = tid & 63;
    const int w    = tid >> 6;
    const int wr   = w >> 1;
    const int wc   = w & 1;
    const int l15  = lane & 15;
    const int lk   = lane >> 4;
    const int rswz = (l15 & 7) << 4;

    f32x4 acc[2][4] = {};

    const char* WTc = (const char*)WT;
    const unsigned char* arow0 = am_raw + (wr * 32 + l15) * 512;
    const unsigned char* arow1 = arow0 + 16 * 512;

    #pragma unroll
    for (int ks = 0; ks < 8; ++ks) {
        int kbyte = ks * 64 + lk * 16;
        int akoff = kbyte ^ rswz;
        short8 a0 = *(const short8*)(arow0 + akoff);
        short8 a1 = *(const short8*)(arow1 + akoff);
        short8 bfr[4];
        #pragma unroll
        for (int nc = 0; nc < 4; ++nc) {
            int col = wc * 64 + nc * 16 + l15;
            bfr[nc] = *(const short8*)(WTc + col * 512 + kbyte);
        }
        #pragma unroll
        for (int nc = 0; nc < 4; ++nc) {
            acc[0][nc] = __builtin_amdgcn_mfma_f32_16x16x32_bf16(a0, bfr[nc], acc[0][nc], 0, 0, 0);
            acc[1][nc] = __builtin_amdgcn_mfma_f32_16x16x32_bf16(a1, bfr[nc], acc[1][nc], 0, 0, 0);
        }
    }

    #pragma unroll
    for (int nc = 0; nc < 4; ++nc) {
        int col = wc * 64 + nc * 16 + l15;
        float bias = b1[col] + b2[col];
        #pragma unroll
        for (int mr = 0; mr < 2; ++mr) {
            int rbase = block0 + wr * 32 + mr * 16 + lk * 4;
            #pragma unroll
            for (int r = 0; r < 4; ++r) {
                int row = rbase + r;
                if (row < N) {
                    float v = acc[mr][nc][r] + bias;
                    out[row * 128 + col] = (v >= 0.f) ? v : 0.01f * v;
                }
            }
        }
    }
}

// ===========================================================================
// Tier-1b/2 CSR kernels (round-3/4, proven)
// ===========================================================================
__global__ __launch_bounds__(256) void hist_kernel(
    const int* __restrict__ rows, int* __restrict__ counts, int E)
{
    int e = blockIdx.x * 256 + threadIdx.x;
    if (e < E) atomicAdd(&counts[rows[e]], 1);
}

__global__ __launch_bounds__(256) void scan_pass1(
    const int* __restrict__ counts, int* __restrict__ btot, int N)
{
    int tid = threadIdx.x;
    int i = blockIdx.x * 1024 + tid * 4;
    int s = 0;
    if (i + 3 < N) {
        int4 v = *(const int4*)(counts + i);
        s = v.x + v.y + v.z + v.w;
    } else {
        for (int q = 0; q < 4; ++q) if (i + q < N) s += counts[i + q];
    }
    #pragma unroll
    for (int off = 32; off >= 1; off >>= 1) s += __shfl_down(s, off, 64);
    __shared__ int ws[4];
    if ((tid & 63) == 0) ws[tid >> 6] = s;
    __syncthreads();
    if (tid == 0) btot[blockIdx.x] = ws[0] + ws[1] + ws[2] + ws[3];
}

__global__ __launch_bounds__(1024) void scan_pass2(
    const int* __restrict__ btot, int* __restrict__ boff, int nb)
{
    __shared__ int wsum[16];
    int tid = threadIdx.x, lane = tid & 63, wid = tid >> 6;
    int x = (tid < nb) ? btot[tid] : 0;
    int v = x;
    #pragma unroll
    for (int off = 1; off < 64; off <<= 1) {
        int y = __shfl_up(v, off, 64);
        if (lane >= off) v += y;
    }
    if (lane == 63) wsum[wid] = v;
    __syncthreads();
    if (wid == 0 && lane < 16) {
        int s = wsum[lane];
        #pragma unroll
        for (int off = 1; off < 16; off <<= 1) {
            int y = __shfl_up(s, off, 64);
            if (lane >= off) s += y;
        }
        wsum[lane] = s;
    }
    __syncthreads();
    int wexcl = wid ? wsum[wid - 1] : 0;
    if (tid < nb) boff[tid] = wexcl + v - x;
}

__global__ __launch_bounds__(256) void scan_pass3(
    int* __restrict__ row_start, int* __restrict__ cursor,
    const int* __restrict__ boff, int N, int E)
{
    int tid = threadIdx.x;
    int base = blockIdx.x * 1024 + tid * 4;
    int c0 = 0, c1 = 0, c2 = 0, c3 = 0;
    if (base + 3 < N) {
        int4 v = *(const int4*)(row_start + base);
        c0 = v.x; c1 = v.y; c2 = v.z; c3 = v.w;
    } else {
        if (base + 0 < N) c0 = row_start[base + 0];
        if (base + 1 < N) c1 = row_start[base + 1];
        if (base + 2 < N) c2 = row_start[base + 2];
        if (base + 3 < N) c3 = row_start[base + 3];
    }
    int s0 = c0, s1 = s0 + c1, s2 = s1 + c2, s3 = s2 + c3;
    int lane = tid & 63, wid = tid >> 6;
    int v = s3;
    #pragma unroll
    for (int off = 1; off < 64; off <<= 1) {
        int y = __shfl_up(v, off, 64);
        if (lane >= off) v += y;
    }
    __shared__ int ws[4];
    if (lane == 63) ws[wid] = v;
    __syncthreads();
    int wexcl = 0;
    for (int q = 0; q < wid; ++q) wexcl += ws[q];
    int texcl = wexcl + (v - s3) + boff[blockIdx.x];
    int e0 = texcl, e1 = texcl + s0, e2 = texcl + s1, e3 = texcl + s2;
    if (base + 0 < N) { row_start[base + 0] = e0; cursor[base + 0] = e0; }
    if (base + 1 < N) { row_start[base + 1] = e1; cursor[base + 1] = e1; }
    if (base + 2 < N) { row_start[base + 2] = e2; cursor[base + 2] = e2; }
    if (base + 3 < N) { row_start[base + 3] = e3; cursor[base + 3] = e3; }
    if (blockIdx.x == 0 && tid == 0) row_start[N] = E;
}

__global__ __launch_bounds__(256) void scatter_sort_kernel(
    const int* __restrict__ rows, const int* __restrict__ cols,
    const float* __restrict__ vals, int* __restrict__ cursor,
    uint2* __restrict__ sedge, int E)
{
    int e = blockIdx.x * 256 + threadIdx.x;
    if (e < E) {
        int r = rows[e];
        int p = atomicAdd(&cursor[r], 1);
        sedge[p] = make_uint2((unsigned)cols[e], __float_as_uint(vals[e]));
    }
}

__global__ __launch_bounds__(256) void spmm_kernel(
    const float2* __restrict__ feat2,
    const int* __restrict__ row_start,
    const uint2* __restrict__ sedge,
    float2* __restrict__ h2, int N)
{
    int gw = (blockIdx.x * 256 + threadIdx.x) >> 6;
    int lane = threadIdx.x & 63;
    if (gw >= N) return;
    int s = row_start[gw];
    int e = row_start[gw + 1];
    float2 acc = make_float2(0.f, 0.f);
    int j = s;
    for (; j + 1 < e; j += 2) {
        uint2 e0 = sedge[j], e1 = sedge[j + 1];
        float v0 = __uint_as_float(e0.y), v1 = __uint_as_float(e1.y);
        float2 f0 = feat2[(size_t)e0.x * 64 + lane];
        float2 f1 = feat2[(size_t)e1.x * 64 + lane];
        acc.x = fmaf(v0, f0.x, acc.x);
        acc.y = fmaf(v0, f0.y, acc.y);
        acc.x = fmaf(v1, f1.x, acc.x);
        acc.y = fmaf(v1, f1.y, acc.y);
    }
    if (j < e) {
        uint2 e0 = sedge[j];
        float v = __uint_as_float(e0.y);
        float2 f = feat2[(size_t)e0.x * 64 + lane];
        acc.x = fmaf(v, f.x, acc.x);
        acc.y = fmaf(v, f.y, acc.y);
    }
    h2[(size_t)gw * 64 + lane] = acc;
}

__global__ __launch_bounds__(256) void mfma_gemm_kernel(
    const float4* __restrict__ feat4, const float4* __restrict__ h4,
    const unsigned short* __restrict__ WT,
    const float* __restrict__ b1, const float* __restrict__ b2,
    float* __restrict__ out, int N)
{
    __shared__ __align__(16) unsigned char am_raw[64 * 512];
    const int tid = threadIdx.x;
    const int block0 = blockIdx.x * BM;
    #pragma unroll
    for (int it = 0; it < 8; ++it) {
        int idx  = tid + it * 256;
        int node = idx >> 5;
        int p    = idx & 31;
        int g    = block0 + node;
        float4 fv = make_float4(0.f, 0.f, 0.f, 0.f);
        float4 hv = make_float4(0.f, 0.f, 0.f, 0.f);
        if (g < N) { fv = feat4[g * 32 + p]; hv = h4[g * 32 + p]; }
        ushort4 av = make_ushort4(f2bf(fv.x + hv.x), f2bf(fv.y + hv.y),
                                  f2bf(fv.z + hv.z), f2bf(fv.w + hv.w));
        ushort4 mv = make_ushort4(f2bf(fv.x * hv.x), f2bf(fv.y * hv.y),
                                  f2bf(fv.z * hv.z), f2bf(fv.w * hv.w));
        int swz = (node & 7) << 4;
        *(ushort4*)(am_raw + node * 512 + ((p * 8) ^ swz))       = av;
        *(ushort4*)(am_raw + node * 512 + ((256 + p * 8) ^ swz)) = mv;
    }
    __syncthreads();
    const int lane = tid & 63;
    const int w    = tid >> 6;
    const int wr   = w >> 1;
    const int wc   = w & 1;
    const int l15  = lane & 15;
    const int lk   = lane >> 4;
    const int rswz = (l15 & 7) << 4;
    f32x4 acc[2][4] = {};
    const char* WTc = (const char*)WT;
    const unsigned char* arow0 = am_raw + (wr * 32 + l15) * 512;
    const unsigned char* arow1 = arow0 + 16 * 512;
    #pragma unroll
    for (int ks = 0; ks < 8; ++ks) {
        int kbyte = ks * 64 + lk * 16;
        int akoff = kbyte ^ rswz;
        short8 a0 = *(const short8*)(arow0 + akoff);
        short8 a1 = *(const short8*)(arow1 + akoff);
        short8 bfr[4];
        #pragma unroll
        for (int nc = 0; nc < 4; ++nc) {
            int col = wc * 64 + nc * 16 + l15;
            bfr[nc] = *(const short8*)(WTc + col * 512 + kbyte);
        }
        #pragma unroll
        for (int nc = 0; nc < 4; ++nc) {
            acc[0][nc] = __builtin_amdgcn_mfma_f32_16x16x32_bf16(a0, bfr[nc], acc[0][nc], 0, 0, 0);
            acc[1][nc] = __builtin_amdgcn_mfma_f32_16x16x32_bf16(a1, bfr[nc], acc[1][nc], 0, 0, 0);
        }
    }
    #pragma unroll
    for (int nc = 0; nc < 4; ++nc) {
        int col = wc * 64 + nc * 16 + l15;
        float bias = b1[col] + b2[col];
        #pragma unroll
        for (int mr = 0; mr < 2; ++mr) {
            int rbase = block0 + wr * 32 + mr * 16 + lk * 4;
            #pragma unroll
            for (int r = 0; r < 4; ++r) {
                int row = rbase + r;
                if (row < N) {
                    float v = acc[mr][nc][r] + bias;
                    out[row * 128 + col] = (v >= 0.f) ? v : 0.01f * v;
                }
            }
        }
    }
}

// ===========================================================================
// Tier-3: atomic scatter + fp32 VALU GEMM
// ===========================================================================
__global__ __launch_bounds__(256) void edge_scatter_kernel(
    const float4* __restrict__ feat4, const int* __restrict__ rows,
    const int* __restrict__ cols, const float* __restrict__ vals,
    float* __restrict__ h, int E)
{
    int idx = blockIdx.x * 256 + threadIdx.x;
    if (idx >= E * 32) return;
    int e = idx >> 5;
    int p = idx & 31;
    int r = rows[e];
    int c = cols[e];
    float v = vals[e];
    float4 f = feat4[c * 32 + p];
    float* hr = h + (long long)r * D + p * 4;
    unsafeAtomicAdd(hr + 0, v * f.x);
    unsafeAtomicAdd(hr + 1, v * f.y);
    unsafeAtomicAdd(hr + 2, v * f.z);
    unsafeAtomicAdd(hr + 3, v * f.w);
}

__global__ __launch_bounds__(256) void fused_gemm_kernel(
    const float* __restrict__ feat, const float* __restrict__ h,
    const float* __restrict__ W1, const float* __restrict__ b1,
    const float* __restrict__ W2, const float* __restrict__ b2,
    float* __restrict__ out, int N)
{
    __shared__ float a_lds[BM][D];
    __shared__ float m_lds[BM][D];
    const int tid = threadIdx.x;
    const int block0 = blockIdx.x * BM;
    const float4* feat4 = (const float4*)feat;
    const float4* h4    = (const float4*)h;
    #pragma unroll
    for (int it = 0; it < 8; ++it) {
        int idx  = tid + it * 256;
        int node = idx >> 5;
        int p    = idx & 31;
        int gnode = block0 + node;
        float4 fv = make_float4(0.f, 0.f, 0.f, 0.f);
        float4 hv = make_float4(0.f, 0.f, 0.f, 0.f);
        if (gnode < N) { fv = feat4[gnode * 32 + p]; hv = h4[gnode * 32 + p]; }
        float4 av = make_float4(fv.x + hv.x, fv.y + hv.y, fv.z + hv.z, fv.w + hv.w);
        float4 mv = make_float4(fv.x * hv.x, fv.y * hv.y, fv.z * hv.z, fv.w * hv.w);
        *(float4*)&a_lds[node][p * 4] = av;
        *(float4*)&m_lds[node][p * 4] = mv;
    }
    __syncthreads();
    const int c = tid & 31;
    const int g = tid >> 5;
    float acc[8][4] = {};
    const float4* W1v = (const float4*)W1;
    const float4* W2v = (const float4*)W2;
    for (int k = 0; k < D; ++k) {
        float4 w1 = W1v[k * 32 + c];
        float4 w2 = W2v[k * 32 + c];
        #pragma unroll
        for (int t = 0; t < 8; ++t) {
            float av = a_lds[g + 8 * t][k];
            float mv = m_lds[g + 8 * t][k];
            acc[t][0] = fmaf(av, w1.x, fmaf(mv, w2.x, acc[t][0]));
            acc[t][1] = fmaf(av, w1.y, fmaf(mv, w2.y, acc[t][1]));
            acc[t][2] = fmaf(av, w1.z, fmaf(mv, w2.z, acc[t][2]));
            acc[t][3] = fmaf(av, w1.w, fmaf(mv, w2.w, acc[t][3]));
        }
    }
    float4 bb1 = ((const float4*)b1)[c];
    float4 bb2 = ((const float4*)b2)[c];
    const float bx = bb1.x + bb2.x, by = bb1.y + bb2.y;
    const float bz = bb1.z + bb2.z, bw = bb1.w + bb2.w;
    #pragma unroll
    for (int t = 0; t < 8; ++t) {
        int gnode = block0 + g + 8 * t;
        if (gnode >= N) continue;
        float4 o;
        o.x = acc[t][0] + bx; o.y = acc[t][1] + by;
        o.z = acc[t][2] + bz; o.w = acc[t][3] + bw;
        o.x = (o.x >= 0.f) ? o.x : 0.01f * o.x;
        o.y = (o.y >= 0.f) ? o.y : 0.01f * o.y;
        o.z = (o.z >= 0.f) ? o.z : 0.01f * o.z;
        o.w = (o.w >= 0.f) ? o.w : 0.01f * o.w;
        ((float4*)out)[gnode * 32 + c] = o;
    }
}

extern "C" void kernel_launch(void* const* d_in, const int* in_sizes, int n_in,
                              void* d_out, int out_size, void* d_ws, size_t ws_size,
                              hipStream_t stream) {
    const float* feat = (const float*)d_in[0];
    const int*   rows = (const int*)d_in[1];
    const int*   cols = (const int*)d_in[2];
    const float* vals = (const float*)d_in[3];
    const float* W1   = (const float*)d_in[4];
    const float* b1   = (const float*)d_in[5];
    const float* W2   = (const float*)d_in[6];
    const float* b2   = (const float*)d_in[7];

    const int N = in_sizes[0] / D;
    const int E = in_sizes[1];
    float* out = (float*)d_out;

    const int NBK  = (N + 127) >> 7;          // 128-row buckets
    const int Npad = NBK << 7;

    // --- Tier-1a (fused-16): featbf | sedge | WT | row_start | bsedge | bcnt | bstart | bcur
    size_t off = 0;
    unsigned short* featbf = (unsigned short*)d_ws;                off += (size_t)N * D * 2;
    off = (off + 15) & ~(size_t)15;
    uint2* sedge = (uint2*)((char*)d_ws + off);                    off += (size_t)E * 8;
    unsigned short* WT = (unsigned short*)((char*)d_ws + off);     off += 128 * 256 * 2;
    int* row_start = (int*)((char*)d_ws + off);                    off += (size_t)(N + 1) * 4;
    off = (off + 15) & ~(size_t)15;
    uint2* bsedge = (uint2*)((char*)d_ws + off);                   off += (size_t)E * 8;
    int* bcnt   = (int*)((char*)d_ws + off);                       off += (size_t)NBK * 4;
    int* bstart = (int*)((char*)d_ws + off);                       off += (size_t)(NBK + 1) * 4;
    int* bcur   = (int*)((char*)d_ws + off);                       off += (size_t)NBK * 4;
    size_t need1a = off;

    if (ws_size >= need1a && NBK <= 1024 && N <= (1 << 17)) {
        hipMemsetAsync(bcnt, 0, (size_t)NBK * sizeof(int), stream);
        fconv_kernel<<<(N * 32 + 255) / 256, 256, 0, stream>>>(
            (const float4*)feat, (ushort4*)featbf, N * 32);
        wconv_kernel<<<128, 256, 0, stream>>>(W1, W2, WT);
        int epb = (E + 255) / 256;
        bucket_hist_kernel<<<256, 256, 0, stream>>>(rows, bcnt, E, NBK, epb);
        bucket_scan_kernel<<<1, 1024, 0, stream>>>(bcnt, bstart, bcur, NBK, E);
        bucket_scatter_kernel<<<(E + 4095) / 4096, 256, 0, stream>>>(
            rows, cols, vals, bcur, bsedge, E, NBK);
        bucket_sort_kernel<<<NBK, 256, 0, stream>>>(
            bsedge, bstart, sedge, row_start, N, E);
        spmm_gemm16_kernel<<<(N + 15) / 16, 256, 0, stream>>>(
            (const float4*)feat, (const ushort8_t*)featbf, row_start, sedge,
            WT, b1, b2, out, N);
        return;
    }

    // --- Tier-1b: unfused round-6 path (adds ambf, full-CSR build) ---
    const int NB = (N + 1023) / 1024;
    off = 0;
    unsigned char* ambf = (unsigned char*)d_ws;                    off += (size_t)Npad * 512;
    featbf = (unsigned short*)((char*)d_ws + off);                 off += (size_t)N * D * 2;
    off = (off + 15) & ~(size_t)15;
    sedge = (uint2*)((char*)d_ws + off);                           off += (size_t)E * 8;
    WT = (unsigned short*)((char*)d_ws + off);                     off += 128 * 256 * 2;
    row_start = (int*)((char*)d_ws + off);                         off += (size_t)(N + 1) * 4;
    off = (off + 15) & ~(size_t)15;
    int* cursor = (int*)((char*)d_ws + off);                       off += (size_t)N * 4;
    int* btot = (int*)((char*)d_ws + off);                         off += (size_t)NB * 4;
    int* boff = (int*)((char*)d_ws + off);                         off += (size_t)NB * 4;
    size_t need1b = off;

    if (ws_size >= need1b && NB <= 1024) {
        hipMemsetAsync(row_start, 0, (size_t)(N + 1) * sizeof(int), stream);
        fconv_kernel<<<(N * 32 + 255) / 256, 256, 0, stream>>>(
            (const float4*)feat, (ushort4*)featbf, N * 32);
        wconv_kernel<<<128, 256, 0, stream>>>(W1, W2, WT);
        hist_kernel<<<(E + 255) / 256, 256, 0, stream>>>(rows, row_start, E);
        scan_pass1<<<NB, 256, 0, stream>>>(row_start, btot, N);
        scan_pass2<<<1, 1024, 0, stream>>>(btot, boff, NB);
        scan_pass3<<<NB, 256, 0, stream>>>(row_start, cursor, boff, N, E);
        scatter_sort_kernel<<<(E + 255) / 256, 256, 0, stream>>>(
            rows, cols, vals, cursor, sedge, E);
        spmm_ab_kernel<<<(N * 16 + 255) / 256, 256, 0, stream>>>(
            (const float4*)feat, (const ushort8_t*)featbf, row_start, sedge,
            ambf, N);
        mfma_gemm2_kernel<<<(N + BM - 1) / BM, 256, 0, stream>>>(
            ambf, WT, b1, b2, out, N);
        return;
    }

    // --- Tier-2: round-3 fp32 CSR path ---
    off = 0;
    float* h = (float*)d_ws;                           off += (size_t)N * D * 4;
    int* row_start2 = (int*)((char*)d_ws + off);       off += (size_t)(N + 1) * 4;
    int* cursor2    = (int*)((char*)d_ws + off);       off += (size_t)N * 4;
    off = (off + 15) & ~(size_t)15;
    uint2* sedge2   = (uint2*)((char*)d_ws + off);     off += (size_t)E * 8;
    off = (off + 15) & ~(size_t)15;
    unsigned short* WT2 = (unsigned short*)((char*)d_ws + off); off += 128 * 256 * 2;
    int* btot2 = (int*)((char*)d_ws + off);            off += (size_t)NB * 4;
    int* boff2 = (int*)((char*)d_ws + off);            off += (size_t)NB * 4;
    size_t need2 = off;

    if (ws_size >= need2 && NB <= 1024) {
        hipMemsetAsync(row_start2, 0, (size_t)(N + 1) * sizeof(int), stream);
        wconv_kernel<<<128, 256, 0, stream>>>(W1, W2, WT2);
        hist_kernel<<<(E + 255) / 256, 256, 0, stream>>>(rows, row_start2, E);
        scan_pass1<<<NB, 256, 0, stream>>>(row_start2, btot2, N);
        scan_pass2<<<1, 1024, 0, stream>>>(btot2, boff2, NB);
        scan_pass3<<<NB, 256, 0, stream>>>(row_start2, cursor2, boff2, N, E);
        scatter_sort_kernel<<<(E + 255) / 256, 256, 0, stream>>>(
            rows, cols, vals, cursor2, sedge2, E);
        spmm_kernel<<<(N * 64 + 255) / 256, 256, 0, stream>>>(
            (const float2*)feat, row_start2, sedge2, (float2*)h, N);
        mfma_gemm_kernel<<<(N + BM - 1) / BM, 256, 0, stream>>>(
            (const float4*)feat, (const float4*)h, WT2, b1, b2, out, N);
        return;
    }

    // --- Tier-3: atomic scatter + VALU GEMM ---
    size_t hbytes = (size_t)N * D * sizeof(float);
    float* hh = (ws_size >= hbytes) ? (float*)d_ws : out;
    hipMemsetAsync(hh, 0, hbytes, stream);
    edge_scatter_kernel<<<((size_t)E * 32 + 255) / 256, 256, 0, stream>>>(
        (const float4*)feat, rows, cols, vals, hh, E);
    fused_gemm_kernel<<<(N + BM - 1) / BM, 256, 0, stream>>>(
        feat, hh, W1, b1, W2, b2, out, N);
}

// Round 9
// 182.870 us; speedup vs baseline: 7.8801x; 1.0096x over previous
//
#include <hip/hip_runtime.h>

#define D 128
#define BM 64

typedef short short8 __attribute__((ext_vector_type(8)));
typedef unsigned short ushort8_t __attribute__((ext_vector_type(8)));
typedef float f32x4 __attribute__((ext_vector_type(4)));

__device__ __forceinline__ unsigned short f2bf(float x) {
    unsigned u = __float_as_uint(x);
    unsigned r = (u + 0x7fffu + ((u >> 16) & 1u)) >> 16;   // RNE
    return (unsigned short)r;
}
__device__ __forceinline__ float bf2f(unsigned short u) {
    return __uint_as_float(((unsigned)u) << 16);
}

// ===========================================================================
// PREP (fused): features fp32->bf16  +  WT build  +  bucket histogram.
// 256 blocks x 256 thr. fconv is BW-bound, hist is atomic-bound -> overlap.
// ===========================================================================
__global__ __launch_bounds__(256) void prep_kernel(
    const float4* __restrict__ feat4, ushort4* __restrict__ fbf4, int nf4,
    const float* __restrict__ W1, const float* __restrict__ W2,
    unsigned short* __restrict__ WT,
    const int* __restrict__ rows, int* __restrict__ bcnt,
    int E, int nb, int epb)
{
    __shared__ int cnt[1024];
    const int t = threadIdx.x;
    const int b = blockIdx.x;
    for (int i = t; i < nb; i += 256) cnt[i] = 0;
    __syncthreads();

    // bucket histogram for this block's edge slice (LDS-aggregated)
    int e0 = b * epb;
    int e1 = e0 + epb; if (e1 > E) e1 = E;
    for (int e = e0 + t; e < e1; e += 256) atomicAdd(&cnt[rows[e] >> 7], 1);

    // feature conversion, grid-stride
    for (int i = b * 256 + t; i < nf4; i += 256 * 256) {
        float4 v = feat4[i];
        fbf4[i] = make_ushort4(f2bf(v.x), f2bf(v.y), f2bf(v.z), f2bf(v.w));
    }

    // WT[c][k] = (k<128 ? W1[k][c] : W2[k-128][c]) ; 32768 elems on blocks 0..127
    if (b < 128) {
        int idx = b * 256 + t;
        int c = idx & 127;
        int k = idx >> 7;
        float w = (k < 128) ? W1[k * 128 + c] : W2[(k - 128) * 128 + c];
        WT[c * 256 + k] = f2bf(w);
    }

    __syncthreads();
    for (int i = t; i < nb; i += 256)
        if (cnt[i]) atomicAdd(&bcnt[i], cnt[i]);
}

// ===========================================================================
// Standalone fconv/wconv (fallback tiers)
// ===========================================================================
__global__ __launch_bounds__(256) void fconv_kernel(
    const float4* __restrict__ feat4, ushort4* __restrict__ fbf4, int total)
{
    int i = blockIdx.x * 256 + threadIdx.x;
    if (i < total) {
        float4 v = feat4[i];
        fbf4[i] = make_ushort4(f2bf(v.x), f2bf(v.y), f2bf(v.z), f2bf(v.w));
    }
}

__global__ __launch_bounds__(256) void wconv_kernel(
    const float* __restrict__ W1, const float* __restrict__ W2,
    unsigned short* __restrict__ WT)
{
    int idx = blockIdx.x * 256 + threadIdx.x;
    int c = idx & 127;
    int k = idx >> 7;
    float w = (k < 128) ? W1[k * 128 + c] : W2[(k - 128) * 128 + c];
    WT[c * 256 + k] = f2bf(w);
}

// ===========================================================================
// Bucket CSR build: scan -> grouped scatter -> per-bucket local sort.
// Buckets are 128 rows; edge key = (r&127)<<17 | col (needs N <= 2^17).
// ===========================================================================
__global__ __launch_bounds__(1024) void bucket_scan_kernel(
    const int* __restrict__ bcnt, int* __restrict__ bstart,
    int* __restrict__ bcur, int nb, int E)
{
    __shared__ int wsum[16];
    int tid = threadIdx.x, lane = tid & 63, wid = tid >> 6;
    int x = (tid < nb) ? bcnt[tid] : 0;
    int v = x;
    #pragma unroll
    for (int off = 1; off < 64; off <<= 1) {
        int y = __shfl_up(v, off, 64);
        if (lane >= off) v += y;
    }
    if (lane == 63) wsum[wid] = v;
    __syncthreads();
    if (wid == 0 && lane < 16) {
        int s = wsum[lane];
        #pragma unroll
        for (int off = 1; off < 16; off <<= 1) {
            int y = __shfl_up(s, off, 64);
            if (lane >= off) s += y;
        }
        wsum[lane] = s;
    }
    __syncthreads();
    int wexcl = wid ? wsum[wid - 1] : 0;
    int excl = wexcl + v - x;
    if (tid < nb) { bstart[tid] = excl; bcur[tid] = excl; }
    if (tid == 0) bstart[nb] = E;
}

__global__ __launch_bounds__(256) void bucket_scatter_kernel(
    const int* __restrict__ rows, const int* __restrict__ cols,
    const float* __restrict__ vals, int* __restrict__ bcur,
    uint2* __restrict__ bsedge, int E, int nb)
{
    __shared__ int cnt[1024];
    __shared__ int base[1024];
    int t = threadIdx.x;
    int e0 = blockIdx.x * 4096;
    for (int i = t; i < nb; i += 256) cnt[i] = 0;
    __syncthreads();
    #pragma unroll
    for (int q = 0; q < 16; ++q) {
        int e = e0 + t + q * 256;
        if (e < E) atomicAdd(&cnt[rows[e] >> 7], 1);
    }
    __syncthreads();
    for (int i = t; i < nb; i += 256) {
        int c = cnt[i];
        if (c) { base[i] = atomicAdd(&bcur[i], c); cnt[i] = 0; }
    }
    __syncthreads();
    #pragma unroll
    for (int q = 0; q < 16; ++q) {
        int e = e0 + t + q * 256;
        if (e < E) {
            int r = rows[e];
            int b = r >> 7;
            int pos = base[b] + atomicAdd(&cnt[b], 1);
            bsedge[pos] = make_uint2(((unsigned)(r & 127) << 17) | (unsigned)cols[e],
                                     __float_as_uint(vals[e]));
        }
    }
}

__global__ __launch_bounds__(256) void bucket_sort_kernel(
    const uint2* __restrict__ bsedge,
    const int* __restrict__ bstart,
    uint2* __restrict__ sedge,
    int* __restrict__ row_start,
    int N, int E)
{
    __shared__ int cnt[128];
    __shared__ int base[128];
    const int b = blockIdx.x;
    const int t = threadIdx.x;
    const int s = bstart[b], e = bstart[b + 1];
    if (t < 128) cnt[t] = 0;
    __syncthreads();
    for (int j = s + t; j < e; j += 256)
        atomicAdd(&cnt[bsedge[j].x >> 17], 1);
    __syncthreads();
    if (t < 64) {
        int c0 = cnt[2 * t], c1 = cnt[2 * t + 1];
        int pair = c0 + c1;
        int v = pair;
        #pragma unroll
        for (int off = 1; off < 64; off <<= 1) {
            int y = __shfl_up(v, off, 64);
            if (t >= off) v += y;
        }
        int excl = v - pair;
        base[2 * t]     = excl;
        base[2 * t + 1] = excl + c0;
        cnt[2 * t] = 0;
        cnt[2 * t + 1] = 0;
    }
    __syncthreads();
    const int r0 = b << 7;
    if (t < 128 && r0 + t < N) row_start[r0 + t] = s + base[t];
    if (b == 0 && t == 0) row_start[N] = E;
    for (int j = s + t; j < e; j += 256) {
        uint2 ed = bsedge[j];
        int rl = ed.x >> 17;
        int p = atomicAdd(&cnt[rl], 1);
        sedge[s + base[rl] + p] = make_uint2(ed.x & 0x1FFFFu, ed.y);
    }
}

// ===========================================================================
// FUSED SpMM + MFMA GEMM, 16-row blocks. All-bf16 inputs:
// Phase 1: one row per 16-lane group, 8-edge unroll (8 x 16B loads in
//   flight/lane), own-row f from featbf, a/m bf16 -> 8KB swizzled LDS.
// Phase 2: 4 waves x 32 cols; 8 k-steps x {1 A ds_read, 2 WT, 2 MFMA}.
// ===========================================================================
__global__ __launch_bounds__(256) void spmm_gemm16_kernel(
    const ushort8_t* __restrict__ fbf8,
    const int* __restrict__ row_start,
    const uint2* __restrict__ sedge,
    const unsigned short* __restrict__ WT,
    const float* __restrict__ b1, const float* __restrict__ b2,
    float* __restrict__ out, int N)
{
    __shared__ __align__(16) unsigned char am_raw[16 * 512];   // 8KB

    const int tid = threadIdx.x;
    const int block0 = blockIdx.x * 16;
    const int rq = tid >> 4;      // 0..15 row slot
    const int l  = tid & 15;      // 16 lanes x 8 bf16 = 128 cols

    int row = block0 + rq;
    float acc[8] = {};
    float f[8] = {};
    if (row < N) {
        int s = row_start[row];
        int e = row_start[row + 1];
        int j = s;
        for (; j + 7 < e; j += 8) {
            uint2 ed[8];
            #pragma unroll
            for (int q = 0; q < 8; ++q) ed[q] = sedge[j + q];
            ushort8_t ff[8];
            #pragma unroll
            for (int q = 0; q < 8; ++q)
                ff[q] = fbf8[(size_t)ed[q].x * 16 + l];
            #pragma unroll
            for (int q = 0; q < 8; ++q) {
                float v = __uint_as_float(ed[q].y);
                #pragma unroll
                for (int p = 0; p < 8; ++p)
                    acc[p] = fmaf(v, bf2f(ff[q][p]), acc[p]);
            }
        }
        for (; j + 3 < e; j += 4) {
            uint2 e0 = sedge[j],     e1 = sedge[j + 1];
            uint2 e2 = sedge[j + 2], e3 = sedge[j + 3];
            ushort8_t f0 = fbf8[(size_t)e0.x * 16 + l];
            ushort8_t f1 = fbf8[(size_t)e1.x * 16 + l];
            ushort8_t f2 = fbf8[(size_t)e2.x * 16 + l];
            ushort8_t f3 = fbf8[(size_t)e3.x * 16 + l];
            float v0 = __uint_as_float(e0.y), v1 = __uint_as_float(e1.y);
            float v2 = __uint_as_float(e2.y), v3 = __uint_as_float(e3.y);
            #pragma unroll
            for (int p = 0; p < 8; ++p) {
                acc[p] = fmaf(v0, bf2f(f0[p]), acc[p]);
                acc[p] = fmaf(v1, bf2f(f1[p]), acc[p]);
                acc[p] = fmaf(v2, bf2f(f2[p]), acc[p]);
                acc[p] = fmaf(v3, bf2f(f3[p]), acc[p]);
            }
        }
        for (; j < e; ++j) {
            uint2 e0 = sedge[j];
            float v = __uint_as_float(e0.y);
            ushort8_t f0 = fbf8[(size_t)e0.x * 16 + l];
            #pragma unroll
            for (int p = 0; p < 8; ++p) acc[p] = fmaf(v, bf2f(f0[p]), acc[p]);
        }
        ushort8_t fown = fbf8[(size_t)row * 16 + l];
        #pragma unroll
        for (int p = 0; p < 8; ++p) f[p] = bf2f(fown[p]);
    }
    ushort8_t av, mv;
    #pragma unroll
    for (int q = 0; q < 8; ++q) {
        av[q] = f2bf(f[q] + acc[q]);
        mv[q] = f2bf(f[q] * acc[q]);
    }
    {
        int swz = (rq & 7) << 4;
        unsigned char* rowp = am_raw + rq * 512;
        *(ushort8_t*)(rowp + ((16 * l) ^ swz))       = av;
        *(ushort8_t*)(rowp + 256 + ((16 * l) ^ swz)) = mv;
    }
    __syncthreads();

    // --- GEMM phase: wave w covers cols w*32..w*32+31 ---
    const int lane = tid & 63;
    const int w    = tid >> 6;
    const int l15  = lane & 15;
    const int lk   = lane >> 4;
    const int rswz = (l15 & 7) << 4;

    f32x4 gacc[2] = {};
    const char* WTc = (const char*)WT;
    const unsigned char* arow = am_raw + l15 * 512;

    #pragma unroll
    for (int ks = 0; ks < 8; ++ks) {
        int kbyte = ks * 64 + lk * 16;
        short8 a = *(const short8*)(arow + (kbyte ^ rswz));
        #pragma unroll
        for (int nc = 0; nc < 2; ++nc) {
            int col = w * 32 + nc * 16 + l15;
            short8 b = *(const short8*)(WTc + col * 512 + kbyte);
            gacc[nc] = __builtin_amdgcn_mfma_f32_16x16x32_bf16(a, b, gacc[nc], 0, 0, 0);
        }
    }

    #pragma unroll
    for (int nc = 0; nc < 2; ++nc) {
        int col = w * 32 + nc * 16 + l15;
        float bias = b1[col] + b2[col];
        int rbase = block0 + lk * 4;
        #pragma unroll
        for (int r = 0; r < 4; ++r) {
            int orow = rbase + r;
            if (orow < N) {
                float v = gacc[nc][r] + bias;
                out[orow * 128 + col] = (v >= 0.f) ? v : 0.01f * v;
            }
        }
    }
}

// ===========================================================================
// Tier-1b kernels: unfused spmm_ab + mfma_gemm2 (round-6 proven)
// ===========================================================================
__global__ __launch_bounds__(256) void spmm_ab_kernel(
    const float4* __restrict__ feat4,
    const ushort8_t* __restrict__ fbf8,
    const int* __restrict__ row_start,
    const uint2* __restrict__ sedge,
    unsigned char* __restrict__ ambf, int N)
{
    int t = blockIdx.x * 256 + threadIdx.x;
    int row = t >> 4;
    int l   = t & 15;
    if (row >= N) return;

    int s = row_start[row];
    int e = row_start[row + 1];

    float acc[8] = {};
    int j = s;
    for (; j + 1 < e; j += 2) {
        uint2 e0 = sedge[j], e1 = sedge[j + 1];
        float v0 = __uint_as_float(e0.y), v1 = __uint_as_float(e1.y);
        ushort8_t f0 = fbf8[(size_t)e0.x * 16 + l];
        ushort8_t f1 = fbf8[(size_t)e1.x * 16 + l];
        #pragma unroll
        for (int q = 0; q < 8; ++q) {
            acc[q] = fmaf(v0, bf2f(f0[q]), acc[q]);
            acc[q] = fmaf(v1, bf2f(f1[q]), acc[q]);
        }
    }
    if (j < e) {
        uint2 e0 = sedge[j];
        float v = __uint_as_float(e0.y);
        ushort8_t f = fbf8[(size_t)e0.x * 16 + l];
        #pragma unroll
        for (int q = 0; q < 8; ++q) acc[q] = fmaf(v, bf2f(f[q]), acc[q]);
    }

    float4 fa = feat4[(size_t)row * 32 + 2 * l];
    float4 fb = feat4[(size_t)row * 32 + 2 * l + 1];
    float f[8] = { fa.x, fa.y, fa.z, fa.w, fb.x, fb.y, fb.z, fb.w };

    ushort8_t av, mv;
    #pragma unroll
    for (int q = 0; q < 8; ++q) {
        av[q] = f2bf(f[q] + acc[q]);
        mv[q] = f2bf(f[q] * acc[q]);
    }

    int swz = (row & 7) << 4;
    unsigned char* rowp = ambf + (size_t)row * 512;
    *(ushort8_t*)(rowp + ((16 * l) ^ swz))       = av;
    *(ushort8_t*)(rowp + 256 + ((16 * l) ^ swz)) = mv;
}

__global__ __launch_bounds__(256) void mfma_gemm2_kernel(
    const unsigned char* __restrict__ ambf,
    const unsigned short* __restrict__ WT,
    const float* __restrict__ b1, const float* __restrict__ b2,
    float* __restrict__ out, int N)
{
    __shared__ __align__(16) unsigned char am_raw[64 * 512];

    const int tid = threadIdx.x;
    const int block0 = blockIdx.x * BM;

    const short8* src = (const short8*)(ambf + (size_t)block0 * 512);
    short8* dst = (short8*)am_raw;
    #pragma unroll
    for (int it = 0; it < 8; ++it) {
        int idx = tid + it * 256;
        dst[idx] = src[idx];
    }
    __syncthreads();

    const int lane = tid & 63;
    const int w    = tid >> 6;
    const int wr   = w >> 1;
    const int wc   = w & 1;
    const int l15  = lane & 15;
    const int lk   = lane >> 4;
    const int rswz = (l15 & 7) << 4;

    f32x4 acc[2][4] = {};

    const char* WTc = (const char*)WT;
    const unsigned char* arow0 = am_raw + (wr * 32 + l15) * 512;
    const unsigned char* arow1 = arow0 + 16 * 512;

    #pragma unroll
    for (int ks = 0; ks < 8; ++ks) {
        int kbyte = ks * 64 + lk * 16;
        int akoff = kbyte ^ rswz;
        short8 a0 = *(const short8*)(arow0 + akoff);
        short8 a1 = *(const short8*)(arow1 + akoff);
        short8 bfr[4];
        #pragma unroll
        for (int nc = 0; nc < 4; ++nc) {
            int col = wc * 64 + nc * 16 + l15;
            bfr[nc] = *(const short8*)(WTc + col * 512 + kbyte);
        }
        #pragma unroll
        for (int nc = 0; nc < 4; ++nc) {
            acc[0][nc] = __builtin_amdgcn_mfma_f32_16x16x32_bf16(a0, bfr[nc], acc[0][nc], 0, 0, 0);
            acc[1][nc] = __builtin_amdgcn_mfma_f32_16x16x32_bf16(a1, bfr[nc], acc[1][nc], 0, 0, 0);
        }
    }

    #pragma unroll
    for (int nc = 0; nc < 4; ++nc) {
        int col = wc * 64 + nc * 16 + l15;
        float bias = b1[col] + b2[col];
        #pragma unroll
        for (int mr = 0; mr < 2; ++mr) {
            int rbase = block0 + wr * 32 + mr * 16 + lk * 4;
            #pragma unroll
            for (int r = 0; r < 4; ++r) {
                int row = rbase + r;
                if (row < N) {
                    float v = acc[mr][nc][r] + bias;
                    out[row * 128 + col] = (v >= 0.f) ? v : 0.01f * v;
                }
            }
        }
    }
}

// ===========================================================================
// Tier-1b/2 CSR kernels (round-3/4, proven)
// ===========================================================================
__global__ __launch_bounds__(256) void hist_kernel(
    const int* __restrict__ rows, int* __restrict__ counts, int E)
{
    int e = blockIdx.x * 256 + threadIdx.x;
    if (e < E) atomicAdd(&counts[rows[e]], 1);
}

__global__ __launch_bounds__(256) void scan_pass1(
    const int* __restrict__ counts, int* __restrict__ btot, int N)
{
    int tid = threadIdx.x;
    int i = blockIdx.x * 1024 + tid * 4;
    int s = 0;
    if (i + 3 < N) {
        int4 v = *(const int4*)(counts + i);
        s = v.x + v.y + v.z + v.w;
    } else {
        for (int q = 0; q < 4; ++q) if (i + q < N) s += counts[i + q];
    }
    #pragma unroll
    for (int off = 32; off >= 1; off >>= 1) s += __shfl_down(s, off, 64);
    __shared__ int ws[4];
    if ((tid & 63) == 0) ws[tid >> 6] = s;
    __syncthreads();
    if (tid == 0) btot[blockIdx.x] = ws[0] + ws[1] + ws[2] + ws[3];
}

__global__ __launch_bounds__(1024) void scan_pass2(
    const int* __restrict__ btot, int* __restrict__ boff, int nb)
{
    __shared__ int wsum[16];
    int tid = threadIdx.x, lane = tid & 63, wid = tid >> 6;
    int x = (tid < nb) ? btot[tid] : 0;
    int v = x;
    #pragma unroll
    for (int off = 1; off < 64; off <<= 1) {
        int y = __shfl_up(v, off, 64);
        if (lane >= off) v += y;
    }
    if (lane == 63) wsum[wid] = v;
    __syncthreads();
    if (wid == 0 && lane < 16) {
        int s = wsum[lane];
        #pragma unroll
        for (int off = 1; off < 16; off <<= 1) {
            int y = __shfl_up(s, off, 64);
            if (lane >= off) s += y;
        }
        wsum[lane] = s;
    }
    __syncthreads();
    int wexcl = wid ? wsum[wid - 1] : 0;
    if (tid < nb) boff[tid] = wexcl + v - x;
}

__global__ __launch_bounds__(256) void scan_pass3(
    int* __restrict__ row_start, int* __restrict__ cursor,
    const int* __restrict__ boff, int N, int E)
{
    int tid = threadIdx.x;
    int base = blockIdx.x * 1024 + tid * 4;
    int c0 = 0, c1 = 0, c2 = 0, c3 = 0;
    if (base + 3 < N) {
        int4 v = *(const int4*)(row_start + base);
        c0 = v.x; c1 = v.y; c2 = v.z; c3 = v.w;
    } else {
        if (base + 0 < N) c0 = row_start[base + 0];
        if (base + 1 < N) c1 = row_start[base + 1];
        if (base + 2 < N) c2 = row_start[base + 2];
        if (base + 3 < N) c3 = row_start[base + 3];
    }
    int s0 = c0, s1 = s0 + c1, s2 = s1 + c2, s3 = s2 + c3;
    int lane = tid & 63, wid = tid >> 6;
    int v = s3;
    #pragma unroll
    for (int off = 1; off < 64; off <<= 1) {
        int y = __shfl_up(v, off, 64);
        if (lane >= off) v += y;
    }
    __shared__ int ws[4];
    if (lane == 63) ws[wid] = v;
    __syncthreads();
    int wexcl = 0;
    for (int q = 0; q < wid; ++q) wexcl += ws[q];
    int texcl = wexcl + (v - s3) + boff[blockIdx.x];
    int e0 = texcl, e1 = texcl + s0, e2 = texcl + s1, e3 = texcl + s2;
    if (base + 0 < N) { row_start[base + 0] = e0; cursor[base + 0] = e0; }
    if (base + 1 < N) { row_start[base + 1] = e1; cursor[base + 1] = e1; }
    if (base + 2 < N) { row_start[base + 2] = e2; cursor[base + 2] = e2; }
    if (base + 3 < N) { row_start[base + 3] = e3; cursor[base + 3] = e3; }
    if (blockIdx.x == 0 && tid == 0) row_start[N] = E;
}

__global__ __launch_bounds__(256) void scatter_sort_kernel(
    const int* __restrict__ rows, const int* __restrict__ cols,
    const float* __restrict__ vals, int* __restrict__ cursor,
    uint2* __restrict__ sedge, int E)
{
    int e = blockIdx.x * 256 + threadIdx.x;
    if (e < E) {
        int r = rows[e];
        int p = atomicAdd(&cursor[r], 1);
        sedge[p] = make_uint2((unsigned)cols[e], __float_as_uint(vals[e]));
    }
}

__global__ __launch_bounds__(256) void spmm_kernel(
    const float2* __restrict__ feat2,
    const int* __restrict__ row_start,
    const uint2* __restrict__ sedge,
    float2* __restrict__ h2, int N)
{
    int gw = (blockIdx.x * 256 + threadIdx.x) >> 6;
    int lane = threadIdx.x & 63;
    if (gw >= N) return;
    int s = row_start[gw];
    int e = row_start[gw + 1];
    float2 acc = make_float2(0.f, 0.f);
    int j = s;
    for (; j + 1 < e; j += 2) {
        uint2 e0 = sedge[j], e1 = sedge[j + 1];
        float v0 = __uint_as_float(e0.y), v1 = __uint_as_float(e1.y);
        float2 f0 = feat2[(size_t)e0.x * 64 + lane];
        float2 f1 = feat2[(size_t)e1.x * 64 + lane];
        acc.x = fmaf(v0, f0.x, acc.x);
        acc.y = fmaf(v0, f0.y, acc.y);
        acc.x = fmaf(v1, f1.x, acc.x);
        acc.y = fmaf(v1, f1.y, acc.y);
    }
    if (j < e) {
        uint2 e0 = sedge[j];
        float v = __uint_as_float(e0.y);
        float2 f = feat2[(size_t)e0.x * 64 + lane];
        acc.x = fmaf(v, f.x, acc.x);
        acc.y = fmaf(v, f.y, acc.y);
    }
    h2[(size_t)gw * 64 + lane] = acc;
}

__global__ __launch_bounds__(256) void mfma_gemm_kernel(
    const float4* __restrict__ feat4, const float4* __restrict__ h4,
    const unsigned short* __restrict__ WT,
    const float* __restrict__ b1, const float* __restrict__ b2,
    float* __restrict__ out, int N)
{
    __shared__ __align__(16) unsigned char am_raw[64 * 512];
    const int tid = threadIdx.x;
    const int block0 = blockIdx.x * BM;
    #pragma unroll
    for (int it = 0; it < 8; ++it) {
        int idx  = tid + it * 256;
        int node = idx >> 5;
        int p    = idx & 31;
        int g    = block0 + node;
        float4 fv = make_float4(0.f, 0.f, 0.f, 0.f);
        float4 hv = make_float4(0.f, 0.f, 0.f, 0.f);
        if (g < N) { fv = feat4[g * 32 + p]; hv = h4[g * 32 + p]; }
        ushort4 av = make_ushort4(f2bf(fv.x + hv.x), f2bf(fv.y + hv.y),
                                  f2bf(fv.z + hv.z), f2bf(fv.w + hv.w));
        ushort4 mv = make_ushort4(f2bf(fv.x * hv.x), f2bf(fv.y * hv.y),
                                  f2bf(fv.z * hv.z), f2bf(fv.w * hv.w));
        int swz = (node & 7) << 4;
        *(ushort4*)(am_raw + node * 512 + ((p * 8) ^ swz))       = av;
        *(ushort4*)(am_raw + node * 512 + ((256 + p * 8) ^ swz)) = mv;
    }
    __syncthreads();
    const int lane = tid & 63;
    const int w    = tid >> 6;
    const int wr   = w >> 1;
    const int wc   = w & 1;
    const int l15  = lane & 15;
    const int lk   = lane >> 4;
    const int rswz = (l15 & 7) << 4;
    f32x4 acc[2][4] = {};
    const char* WTc = (const char*)WT;
    const unsigned char* arow0 = am_raw + (wr * 32 + l15) * 512;
    const unsigned char* arow1 = arow0 + 16 * 512;
    #pragma unroll
    for (int ks = 0; ks < 8; ++ks) {
        int kbyte = ks * 64 + lk * 16;
        int akoff = kbyte ^ rswz;
        short8 a0 = *(const short8*)(arow0 + akoff);
        short8 a1 = *(const short8*)(arow1 + akoff);
        short8 bfr[4];
        #pragma unroll
        for (int nc = 0; nc < 4; ++nc) {
            int col = wc * 64 + nc * 16 + l15;
            bfr[nc] = *(const short8*)(WTc + col * 512 + kbyte);
        }
        #pragma unroll
        for (int nc = 0; nc < 4; ++nc) {
            acc[0][nc] = __builtin_amdgcn_mfma_f32_16x16x32_bf16(a0, bfr[nc], acc[0][nc], 0, 0, 0);
            acc[1][nc] = __builtin_amdgcn_mfma_f32_16x16x32_bf16(a1, bfr[nc], acc[1][nc], 0, 0, 0);
        }
    }
    #pragma unroll
    for (int nc = 0; nc < 4; ++nc) {
        int col = wc * 64 + nc * 16 + l15;
        float bias = b1[col] + b2[col];
        #pragma unroll
        for (int mr = 0; mr < 2; ++mr) {
            int rbase = block0 + wr * 32 + mr * 16 + lk * 4;
            #pragma unroll
            for (int r = 0; r < 4; ++r) {
                int row = rbase + r;
                if (row < N) {
                    float v = acc[mr][nc][r] + bias;
                    out[row * 128 + col] = (v >= 0.f) ? v : 0.01f * v;
                }
            }
        }
    }
}

// ===========================================================================
// Tier-3: atomic scatter + fp32 VALU GEMM
// ===========================================================================
__global__ __launch_bounds__(256) void edge_scatter_kernel(
    const float4* __restrict__ feat4, const int* __restrict__ rows,
    const int* __restrict__ cols, const float* __restrict__ vals,
    float* __restrict__ h, int E)
{
    int idx = blockIdx.x * 256 + threadIdx.x;
    if (idx >= E * 32) return;
    int e = idx >> 5;
    int p = idx & 31;
    int r = rows[e];
    int c = cols[e];
    float v = vals[e];
    float4 f = feat4[c * 32 + p];
    float* hr = h + (long long)r * D + p * 4;
    unsafeAtomicAdd(hr + 0, v * f.x);
    unsafeAtomicAdd(hr + 1, v * f.y);
    unsafeAtomicAdd(hr + 2, v * f.z);
    unsafeAtomicAdd(hr + 3, v * f.w);
}

__global__ __launch_bounds__(256) void fused_gemm_kernel(
    const float* __restrict__ feat, const float* __restrict__ h,
    const float* __restrict__ W1, const float* __restrict__ b1,
    const float* __restrict__ W2, const float* __restrict__ b2,
    float* __restrict__ out, int N)
{
    __shared__ float a_lds[BM][D];
    __shared__ float m_lds[BM][D];
    const int tid = threadIdx.x;
    const int block0 = blockIdx.x * BM;
    const float4* feat4 = (const float4*)feat;
    const float4* h4    = (const float4*)h;
    #pragma unroll
    for (int it = 0; it < 8; ++it) {
        int idx  = tid + it * 256;
        int node = idx >> 5;
        int p    = idx & 31;
        int gnode = block0 + node;
        float4 fv = make_float4(0.f, 0.f, 0.f, 0.f);
        float4 hv = make_float4(0.f, 0.f, 0.f, 0.f);
        if (gnode < N) { fv = feat4[gnode * 32 + p]; hv = h4[gnode * 32 + p]; }
        float4 av = make_float4(fv.x + hv.x, fv.y + hv.y, fv.z + hv.z, fv.w + hv.w);
        float4 mv = make_float4(fv.x * hv.x, fv.y * hv.y, fv.z * hv.z, fv.w * hv.w);
        *(float4*)&a_lds[node][p * 4] = av;
        *(float4*)&m_lds[node][p * 4] = mv;
    }
    __syncthreads();
    const int c = tid & 31;
    const int g = tid >> 5;
    float acc[8][4] = {};
    const float4* W1v = (const float4*)W1;
    const float4* W2v = (const float4*)W2;
    for (int k = 0; k < D; ++k) {
        float4 w1 = W1v[k * 32 + c];
        float4 w2 = W2v[k * 32 + c];
        #pragma unroll
        for (int t = 0; t < 8; ++t) {
            float av = a_lds[g + 8 * t][k];
            float mv = m_lds[g + 8 * t][k];
            acc[t][0] = fmaf(av, w1.x, fmaf(mv, w2.x, acc[t][0]));
            acc[t][1] = fmaf(av, w1.y, fmaf(mv, w2.y, acc[t][1]));
            acc[t][2] = fmaf(av, w1.z, fmaf(mv, w2.z, acc[t][2]));
            acc[t][3] = fmaf(av, w1.w, fmaf(mv, w2.w, acc[t][3]));
        }
    }
    float4 bb1 = ((const float4*)b1)[c];
    float4 bb2 = ((const float4*)b2)[c];
    const float bx = bb1.x + bb2.x, by = bb1.y + bb2.y;
    const float bz = bb1.z + bb2.z, bw = bb1.w + bb2.w;
    #pragma unroll
    for (int t = 0; t < 8; ++t) {
        int gnode = block0 + g + 8 * t;
        if (gnode >= N) continue;
        float4 o;
        o.x = acc[t][0] + bx; o.y = acc[t][1] + by;
        o.z = acc[t][2] + bz; o.w = acc[t][3] + bw;
        o.x = (o.x >= 0.f) ? o.x : 0.01f * o.x;
        o.y = (o.y >= 0.f) ? o.y : 0.01f * o.y;
        o.z = (o.z >= 0.f) ? o.z : 0.01f * o.z;
        o.w = (o.w >= 0.f) ? o.w : 0.01f * o.w;
        ((float4*)out)[gnode * 32 + c] = o;
    }
}

extern "C" void kernel_launch(void* const* d_in, const int* in_sizes, int n_in,
                              void* d_out, int out_size, void* d_ws, size_t ws_size,
                              hipStream_t stream) {
    const float* feat = (const float*)d_in[0];
    const int*   rows = (const int*)d_in[1];
    const int*   cols = (const int*)d_in[2];
    const float* vals = (const float*)d_in[3];
    const float* W1   = (const float*)d_in[4];
    const float* b1   = (const float*)d_in[5];
    const float* W2   = (const float*)d_in[6];
    const float* b2   = (const float*)d_in[7];

    const int N = in_sizes[0] / D;
    const int E = in_sizes[1];
    float* out = (float*)d_out;

    const int NBK  = (N + 127) >> 7;          // 128-row buckets
    const int Npad = NBK << 7;

    // --- Tier-1a: featbf | sedge | WT | row_start | bsedge | bcnt | bstart | bcur
    size_t off = 0;
    unsigned short* featbf = (unsigned short*)d_ws;                off += (size_t)N * D * 2;
    off = (off + 15) & ~(size_t)15;
    uint2* sedge = (uint2*)((char*)d_ws + off);                    off += (size_t)E * 8;
    unsigned short* WT = (unsigned short*)((char*)d_ws + off);     off += 128 * 256 * 2;
    int* row_start = (int*)((char*)d_ws + off);                    off += (size_t)(N + 1) * 4;
    off = (off + 15) & ~(size_t)15;
    uint2* bsedge = (uint2*)((char*)d_ws + off);                   off += (size_t)E * 8;
    int* bcnt   = (int*)((char*)d_ws + off);                       off += (size_t)NBK * 4;
    int* bstart = (int*)((char*)d_ws + off);                       off += (size_t)(NBK + 1) * 4;
    int* bcur   = (int*)((char*)d_ws + off);                       off += (size_t)NBK * 4;
    size_t need1a = off;

    if (ws_size >= need1a && NBK <= 1024 && N <= (1 << 17)) {
        hipMemsetAsync(bcnt, 0, (size_t)NBK * sizeof(int), stream);
        int epb = (E + 255) / 256;
        prep_kernel<<<256, 256, 0, stream>>>(
            (const float4*)feat, (ushort4*)featbf, N * 32,
            W1, W2, WT, rows, bcnt, E, NBK, epb);
        bucket_scan_kernel<<<1, 1024, 0, stream>>>(bcnt, bstart, bcur, NBK, E);
        bucket_scatter_kernel<<<(E + 4095) / 4096, 256, 0, stream>>>(
            rows, cols, vals, bcur, bsedge, E, NBK);
        bucket_sort_kernel<<<NBK, 256, 0, stream>>>(
            bsedge, bstart, sedge, row_start, N, E);
        spmm_gemm16_kernel<<<(N + 15) / 16, 256, 0, stream>>>(
            (const ushort8_t*)featbf, row_start, sedge,
            WT, b1, b2, out, N);
        return;
    }

    // --- Tier-1b: unfused round-6 path (adds ambf, full-CSR build) ---
    const int NB = (N + 1023) / 1024;
    off = 0;
    unsigned char* ambf = (unsigned char*)d_ws;                    off += (size_t)Npad * 512;
    featbf = (unsigned short*)((char*)d_ws + off);                 off += (size_t)N * D * 2;
    off = (off + 15) & ~(size_t)15;
    sedge = (uint2*)((char*)d_ws + off);                           off += (size_t)E * 8;
    WT = (unsigned short*)((char*)d_ws + off);                     off += 128 * 256 * 2;
    row_start = (int*)((char*)d_ws + off);                         off += (size_t)(N + 1) * 4;
    off = (off + 15) & ~(size_t)15;
    int* cursor = (int*)((char*)d_ws + off);                       off += (size_t)N * 4;
    int* btot = (int*)((char*)d_ws + off);                         off += (size_t)NB * 4;
    int* boff = (int*)((char*)d_ws + off);                         off += (size_t)NB * 4;
    size_t need1b = off;

    if (ws_size >= need1b && NB <= 1024) {
        hipMemsetAsync(row_start, 0, (size_t)(N + 1) * sizeof(int), stream);
        fconv_kernel<<<(N * 32 + 255) / 256, 256, 0, stream>>>(
            (const float4*)feat, (ushort4*)featbf, N * 32);
        wconv_kernel<<<128, 256, 0, stream>>>(W1, W2, WT);
        hist_kernel<<<(E + 255) / 256, 256, 0, stream>>>(rows, row_start, E);
        scan_pass1<<<NB, 256, 0, stream>>>(row_start, btot, N);
        scan_pass2<<<1, 1024, 0, stream>>>(btot, boff, NB);
        scan_pass3<<<NB, 256, 0, stream>>>(row_start, cursor, boff, N, E);
        scatter_sort_kernel<<<(E + 255) / 256, 256, 0, stream>>>(
            rows, cols, vals, cursor, sedge, E);
        spmm_ab_kernel<<<(N * 16 + 255) / 256, 256, 0, stream>>>(
            (const float4*)feat, (const ushort8_t*)featbf, row_start, sedge,
            ambf, N);
        mfma_gemm2_kernel<<<(N + BM - 1) / BM, 256, 0, stream>>>(
            ambf, WT, b1, b2, out, N);
        return;
    }

    // --- Tier-2: round-3 fp32 CSR path ---
    off = 0;
    float* h = (float*)d_ws;                           off += (size_t)N * D * 4;
    int* row_start2 = (int*)((char*)d_ws + off);       off += (size_t)(N + 1) * 4;
    int* cursor2    = (int*)((char*)d_ws + off);       off += (size_t)N * 4;
    off = (off + 15) & ~(size_t)15;
    uint2* sedge2   = (uint2*)((char*)d_ws + off);     off += (size_t)E * 8;
    off = (off + 15) & ~(size_t)15;
    unsigned short* WT2 = (unsigned short*)((char*)d_ws + off); off += 128 * 256 * 2;
    int* btot2 = (int*)((char*)d_ws + off);            off += (size_t)NB * 4;
    int* boff2 = (int*)((char*)d_ws + off);            off += (size_t)NB * 4;
    size_t need2 = off;

    if (ws_size >= need2 && NB <= 1024) {
        hipMemsetAsync(row_start2, 0, (size_t)(N + 1) * sizeof(int), stream);
        wconv_kernel<<<128, 256, 0, stream>>>(W1, W2, WT2);
        hist_kernel<<<(E + 255) / 256, 256, 0, stream>>>(rows, row_start2, E);
        scan_pass1<<<NB, 256, 0, stream>>>(row_start2, btot2, N);
        scan_pass2<<<1, 1024, 0, stream>>>(btot2, boff2, NB);
        scan_pass3<<<NB, 256, 0, stream>>>(row_start2, cursor2, boff2, N, E);
        scatter_sort_kernel<<<(E + 255) / 256, 256, 0, stream>>>(
            rows, cols, vals, cursor2, sedge2, E);
        spmm_kernel<<<(N * 64 + 255) / 256, 256, 0, stream>>>(
            (const float2*)feat, row_start2, sedge2, (float2*)h, N);
        mfma_gemm_kernel<<<(N + BM - 1) / BM, 256, 0, stream>>>(
            (const float4*)feat, (const float4*)h, WT2, b1, b2, out, N);
        return;
    }

    // --- Tier-3: atomic scatter + VALU GEMM ---
    size_t hbytes = (size_t)N * D * sizeof(float);
    float* hh = (ws_size >= hbytes) ? (float*)d_ws : out;
    hipMemsetAsync(hh, 0, hbytes, stream);
    edge_scatter_kernel<<<((size_t)E * 32 + 255) / 256, 256, 0, stream>>>(
        (const float4*)feat, rows, cols, vals, hh, E);
    fused_gemm_kernel<<<(N + BM - 1) / BM, 256, 0, stream>>>(
        feat, hh, W1, b1, W2, b2, out, N);
}